// Round 6
// baseline (207.893 us; speedup 1.0000x reference)
//
#include <hip/hip_runtime.h>
#include <hip/hip_fp16.h>

#define NTOT 50000
#define N0 20000
#define N1 5000
#define N2 1000
#define E0C 320000
#define E1C 80000
#define E2C 16000

__global__ void hist_all(const int* __restrict__ ei0, const int* __restrict__ ei1,
                         const int* __restrict__ ei2, int* __restrict__ counts) {
    int i = blockIdx.x * blockDim.x + threadIdx.x;
    if (i < E0C) {
        atomicAdd(&counts[ei0[E0C + i]], 1);
    } else if (i < E0C + E1C) {
        int j = i - E0C;
        atomicAdd(&counts[N0 + ei1[E1C + j]], 1);
    } else if (i < E0C + E1C + E2C) {
        int j = i - E0C - E1C;
        atomicAdd(&counts[N0 + N1 + ei2[E2C + j]], 1);
    }
}

__global__ __launch_bounds__(1024) void scan_all(
    const int* __restrict__ counts,
    int* __restrict__ offs0, int* __restrict__ cur0,
    int* __restrict__ offs1, int* __restrict__ cur1,
    int* __restrict__ offs2, int* __restrict__ cur2) {
    int g = blockIdx.x;
    int n = (g == 0) ? N0 : (g == 1) ? N1 : N2;
    const int* cnt = counts + ((g == 0) ? 0 : (g == 1) ? N0 : N0 + N1);
    int* offs = (g == 0) ? offs0 : (g == 1) ? offs1 : offs2;
    int* cur  = (g == 0) ? cur0  : (g == 1) ? cur1  : cur2;
    int t = threadIdx.x;
    int chunk = (n + 1023) >> 10;
    int lo = t * chunk;
    int hi = min(lo + chunk, n);
    int s = 0;
    for (int i = lo; i < hi; i++) s += cnt[i];
    int lane = t & 63, wid = t >> 6;
    int v = s;
    for (int d = 1; d < 64; d <<= 1) {
        int u = __shfl_up(v, d, 64);
        if (lane >= d) v += u;
    }
    __shared__ int wsum[16];
    __shared__ int woff[16];
    if (lane == 63) wsum[wid] = v;
    __syncthreads();
    if (t < 16) {
        int wv = wsum[t];
        int iv = wv;
        for (int d = 1; d < 16; d <<= 1) {
            int u = __shfl_up(iv, d, 64);
            if (t >= d) iv += u;
        }
        woff[t] = iv - wv;
    }
    __syncthreads();
    int run = woff[wid] + v - s;
    for (int i = lo; i < hi; i++) {
        offs[i] = run;
        cur[i] = run;
        run += cnt[i];
    }
    if (lo < n && hi == n) offs[n] = run;
}

__global__ void scatter_all(const int* __restrict__ ei0, const int* __restrict__ ei1,
                            const int* __restrict__ ei2,
                            int* __restrict__ cur0, int* __restrict__ cur1, int* __restrict__ cur2,
                            int* __restrict__ ss0, int* __restrict__ ss1, int* __restrict__ ss2) {
    int i = blockIdx.x * blockDim.x + threadIdx.x;
    if (i < E0C) {
        int d = ei0[E0C + i];
        int pos = atomicAdd(&cur0[d], 1);
        ss0[pos] = ei0[i];
    } else if (i < E0C + E1C) {
        int j = i - E0C;
        int d = ei1[E1C + j];
        int pos = atomicAdd(&cur1[d], 1);
        ss1[pos] = ei1[j];
    } else if (i < E0C + E1C + E2C) {
        int j = i - E0C - E1C;
        int d = ei2[E2C + j];
        int pos = atomicAdd(&cur2[d], 1);
        ss2[pos] = ei2[j];
    }
}

// xt0p[n][b][8] = x[b][n_id[n]][0..4] padded to 8 floats
__global__ void gather_kernel(const float* __restrict__ x, const int* __restrict__ n_id,
                              float* __restrict__ xt0p) {
    int idx = blockIdx.x * blockDim.x + threadIdx.x;
    if (idx >= N0 * 16) return;
    int n = idx >> 4, b = idx & 15;
    const float* p = x + (size_t)b * (NTOT * 5) + (size_t)n_id[n] * 5;
    float* q = xt0p + (size_t)n * 128 + b * 8;
    float4 v0 = {p[0], p[1], p[2], p[3]};
    float4 v1 = {p[4], 0.f, 0.f, 0.f};
    *(float4*)q = v0;
    *(float4*)(q + 4) = v1;
}

// SAGE layer 1: WAVE per dst; lane = es*16+b (4 edge slots). fp32 in, fp16 out.
__global__ __launch_bounds__(256) void sage1_kernel(
    const float* __restrict__ xt0p, const int* __restrict__ offs, const int* __restrict__ ssrc,
    const float* __restrict__ W, const float* __restrict__ bias, __half* __restrict__ xt1h) {
    int d = (blockIdx.x * 256 + threadIdx.x) >> 6;
    int q = threadIdx.x & 63;
    int es = q >> 4, b = q & 15;
    const float* ps = xt0p + (size_t)d * 128 + b * 8;
    float4 x0 = *(const float4*)ps;
    float x4 = ps[4];
    float xs[5] = {x0.x, x0.y, x0.z, x0.w, x4};
    float a[5] = {0.f, 0.f, 0.f, 0.f, 0.f};
    int e0 = offs[d], e1 = offs[d + 1];
    for (int e = e0 + es; e < e1; e += 4) {
        const float* p = xt0p + (size_t)ssrc[e] * 128 + b * 8;
        float4 v = *(const float4*)p;
        float v4 = p[4];
        a[0] += v.x; a[1] += v.y; a[2] += v.z; a[3] += v.w; a[4] += v4;
    }
#pragma unroll
    for (int c = 0; c < 5; c++) {
        a[c] += __shfl_xor(a[c], 16, 64);
        a[c] += __shfl_xor(a[c], 32, 64);
    }
    float inv = 1.f / (float)(e1 - e0 + 1);
#pragma unroll
    for (int c = 0; c < 5; c++) a[c] = (a[c] + xs[c]) * inv;
    float o[6];
#pragma unroll
    for (int j = 0; j < 6; j++) {
        float acc = bias[j];
#pragma unroll
        for (int i = 0; i < 5; i++) acc += xs[i] * W[i * 6 + j];
#pragma unroll
        for (int i = 0; i < 5; i++) acc += a[i] * W[(5 + i) * 6 + j];
        o[j] = acc;
    }
    float nrm = 0.f;
#pragma unroll
    for (int j = 0; j < 6; j++) nrm += o[j] * o[j];
    float r = 1.f / fmaxf(sqrtf(nrm), 1e-12f);
    if (es == 0) {
        union { __half h[8]; uint4 u; } pk;
#pragma unroll
        for (int j = 0; j < 6; j++) pk.h[j] = __float2half_rn(fmaxf(o[j] * r, 0.f));
        pk.h[6] = __half(0.f);
        pk.h[7] = __half(0.f);
        *(uint4*)(xt1h + (size_t)d * 128 + b * 8) = pk.u;
    }
}

// SAGE layer 2: WAVE per dst; 4 edge slots; each slot computes 9 of 36 cols.
// Writes xt2h TRANSPOSED fp16: xt2h[d][c][b].
__global__ __launch_bounds__(256) void sage2_kernel(
    const __half* __restrict__ xt1h, const int* __restrict__ offs, const int* __restrict__ ssrc,
    const float* __restrict__ W, const float* __restrict__ bias, __half* __restrict__ xt2h) {
    int d = (blockIdx.x * 256 + threadIdx.x) >> 6;
    int q = threadIdx.x & 63;
    int es = q >> 4, b = q & 15;
    const __half2* ps = (const __half2*)(xt1h + (size_t)d * 128 + b * 8);
    float2 s01 = __half22float2(ps[0]);
    float2 s23 = __half22float2(ps[1]);
    float2 s45 = __half22float2(ps[2]);
    float xs[6] = {s01.x, s01.y, s23.x, s23.y, s45.x, s45.y};
    float a[6] = {0.f, 0.f, 0.f, 0.f, 0.f, 0.f};
    int e0 = offs[d], e1 = offs[d + 1];
    union { uint4 u; __half2 h2[4]; } pk0;
    for (int e = e0 + es; e < e1; e += 4) {
        pk0.u = *(const uint4*)(xt1h + (size_t)ssrc[e] * 128 + b * 8);
        float2 v01 = __half22float2(pk0.h2[0]);
        float2 v23 = __half22float2(pk0.h2[1]);
        float2 v45 = __half22float2(pk0.h2[2]);
        a[0] += v01.x; a[1] += v01.y; a[2] += v23.x;
        a[3] += v23.y; a[4] += v45.x; a[5] += v45.y;
    }
#pragma unroll
    for (int c = 0; c < 6; c++) {
        a[c] += __shfl_xor(a[c], 16, 64);
        a[c] += __shfl_xor(a[c], 32, 64);
    }
    float inv = 1.f / (float)(e1 - e0 + 1);
#pragma unroll
    for (int c = 0; c < 6; c++) a[c] = (a[c] + xs[c]) * inv;
    int j0 = es * 9;
    float o[9];
#pragma unroll
    for (int jj = 0; jj < 9; jj++) {
        int j = j0 + jj;
        float acc = bias[j];
#pragma unroll
        for (int i = 0; i < 6; i++) acc += xs[i] * W[i * 36 + j];
#pragma unroll
        for (int i = 0; i < 6; i++) acc += a[i] * W[(6 + i) * 36 + j];
        o[jj] = acc;
    }
    float pn = 0.f;
#pragma unroll
    for (int jj = 0; jj < 9; jj++) pn += o[jj] * o[jj];
    pn += __shfl_xor(pn, 16, 64);
    pn += __shfl_xor(pn, 32, 64);
    float r = 1.f / fmaxf(sqrtf(pn), 1e-12f);
    __half* pd = xt2h + (size_t)d * 576 + b;   // [d][c][b], stride 16 per c
#pragma unroll
    for (int jj = 0; jj < 9; jj++) pd[(j0 + jj) * 16] = __float2half_rn(fmaxf(o[jj] * r, 0.f));
}

// Fused layer-3: one 256-thread BLOCK per dst (4 waves).
// Phase A: 4 waves split edges (strided), fp32 partials -> LDS reduce.
// Phase B: column-split matmul — wave w owns cols 54w+q (q<54); W3 scalar from
// global (31KB, L1-resident); agg rows via LDS broadcast. Epilogue: relu+b3,
// W4 projection, butterfly reduce within wave, tiny cross-wave LDS reduce.
__global__ __launch_bounds__(256) void sage3_kernel(
    const __half* __restrict__ xt2h, const int* __restrict__ offs, const int* __restrict__ ssrc,
    const float* __restrict__ W3, const float* __restrict__ b3,
    const float* __restrict__ W4, float* __restrict__ y) {
    __shared__ float sPart[4][576];
    __shared__ float sT[576];
    __shared__ float sRed[4][32];
    int t = threadIdx.x;
    int w = t >> 6, q = t & 63;
    int d = blockIdx.x;
    int e0 = offs[d], e1 = offs[d + 1];

    // phase A: strided 4-way edge split
    float acc[16];
#pragma unroll
    for (int i = 0; i < 16; i++) acc[i] = 0.f;
    const uint4* base = (const uint4*)xt2h;   // node row = 72 uint4 (1152B)
    union { uint4 u; __half2 h2[4]; } c0;
    for (int e = e0 + w; e < e1; e += 4) {
        const uint4* p0 = base + (size_t)ssrc[e] * 72;
        c0.u = p0[q];
#pragma unroll
        for (int j = 0; j < 4; j++) {
            float2 f = __half22float2(c0.h2[j]);
            acc[2 * j] += f.x;
            acc[2 * j + 1] += f.y;
        }
        if (q < 8) {
            c0.u = p0[64 + q];
#pragma unroll
            for (int j = 0; j < 4; j++) {
                float2 f = __half22float2(c0.h2[j]);
                acc[8 + 2 * j] += f.x;
                acc[9 + 2 * j] += f.y;
            }
        }
    }
#pragma unroll
    for (int j = 0; j < 8; j++) sPart[w][q * 8 + j] = acc[j];
    if (q < 8) {
#pragma unroll
        for (int j = 0; j < 8; j++) sPart[w][512 + q * 8 + j] = acc[8 + j];
    }
    __syncthreads();
    float inv = 1.f / fmaxf((float)(e1 - e0), 1.f);
    for (int i = t; i < 576; i += 256)
        sT[i] = (sPart[0][i] + sPart[1][i] + sPart[2][i] + sPart[3][i]) * inv;
    __syncthreads();

    // phase B: wave w -> col j = 54w+q (q<54); out[r] for 16 batch rows
    bool act = (q < 54);
    int j = 54 * w + (act ? q : 0);
    float out[16];
#pragma unroll
    for (int r = 0; r < 16; r++) out[r] = 0.f;
#pragma unroll 4
    for (int c = 0; c < 36; c++) {
        float wv = act ? W3[c * 216 + j] : 0.f;
        const float4* sp = (const float4*)&sT[c * 16];
        float4 s0 = sp[0], s1 = sp[1], s2 = sp[2], s3 = sp[3];
        out[0] = fmaf(s0.x, wv, out[0]);
        out[1] = fmaf(s0.y, wv, out[1]);
        out[2] = fmaf(s0.z, wv, out[2]);
        out[3] = fmaf(s0.w, wv, out[3]);
        out[4] = fmaf(s1.x, wv, out[4]);
        out[5] = fmaf(s1.y, wv, out[5]);
        out[6] = fmaf(s1.z, wv, out[6]);
        out[7] = fmaf(s1.w, wv, out[7]);
        out[8] = fmaf(s2.x, wv, out[8]);
        out[9] = fmaf(s2.y, wv, out[9]);
        out[10] = fmaf(s2.z, wv, out[10]);
        out[11] = fmaf(s2.w, wv, out[11]);
        out[12] = fmaf(s3.x, wv, out[12]);
        out[13] = fmaf(s3.y, wv, out[13]);
        out[14] = fmaf(s3.z, wv, out[14]);
        out[15] = fmaf(s3.w, wv, out[15]);
    }

    // epilogue: +b3, relu, project by W4 (per-col), butterfly reduce
    float vals[32];
#pragma unroll
    for (int i = 0; i < 32; i++) vals[i] = 0.f;
    if (act) {
        float bj = b3[j];
        float w40 = W4[j * 2], w41 = W4[j * 2 + 1];
#pragma unroll
        for (int r = 0; r < 16; r++) {
            float vv = fmaxf(out[r] + bj, 0.f);
            vals[r * 2 + 0] = vv * w40;
            vals[r * 2 + 1] = vv * w41;
        }
    }
#pragma unroll
    for (int i = 0; i < 5; i++) {
        int m = 1 << i;
        int half = 16 >> i;
        bool bit = (q >> i) & 1;
#pragma unroll
        for (int jj = 0; jj < 16; jj++) {
            if (jj < half) {
                float lo_ = vals[jj], hi_ = vals[jj + half];
                float send = bit ? lo_ : hi_;
                float recv = __shfl_xor(send, m, 64);
                vals[jj] = (bit ? hi_ : lo_) + recv;
            }
        }
    }
    float tot = vals[0] + __shfl_xor(vals[0], 32, 64);
    if (q < 32) {
        int v = ((q & 1) << 4) | ((q & 2) << 2) | (q & 4) | ((q & 8) >> 2) | ((q & 16) >> 4);
        sRed[w][v] = tot;
    }
    __syncthreads();
    if (t < 32) y[(size_t)d * 32 + t] = sRed[0][t] + sRed[1][t] + sRed[2][t] + sRed[3][t];
}

// layer 4: mean-agg of projected y over edges2, + b4. out[b][n][k].
__global__ void final_kernel(const float* __restrict__ y, const int* __restrict__ offs,
                             const int* __restrict__ ssrc, const float* __restrict__ b4,
                             float* __restrict__ out) {
    int idx = blockIdx.x * blockDim.x + threadIdx.x;
    if (idx >= N2 * 16) return;
    int d = idx >> 4, b = idx & 15;
    int e0 = offs[d], e1 = offs[d + 1];
    float s0 = 0.f, s1 = 0.f;
    for (int e = e0; e < e1; e++) {
        int s = ssrc[e];
        const float2 v = *(const float2*)(y + (size_t)s * 32 + b * 2);
        s0 += v.x; s1 += v.y;
    }
    float inv = 1.f / fmaxf((float)(e1 - e0), 1.f);
    out[b * (N2 * 2) + d * 2 + 0] = s0 * inv + b4[0];
    out[b * (N2 * 2) + d * 2 + 1] = s1 * inv + b4[1];
}

extern "C" void kernel_launch(void* const* d_in, const int* in_sizes, int n_in,
                              void* d_out, int out_size, void* d_ws, size_t ws_size,
                              hipStream_t stream) {
    const float* x   = (const float*)d_in[0];
    const int* n_id  = (const int*)d_in[1];
    const int* ei0   = (const int*)d_in[2];
    const int* ei1   = (const int*)d_in[3];
    const int* ei2   = (const int*)d_in[4];
    const float* W1  = (const float*)d_in[5];
    const float* b1  = (const float*)d_in[6];
    const float* W2  = (const float*)d_in[7];
    const float* b2  = (const float*)d_in[8];
    const float* W3  = (const float*)d_in[9];
    const float* b3  = (const float*)d_in[10];
    const float* W4  = (const float*)d_in[11];
    const float* b4  = (const float*)d_in[12];
    float* out = (float*)d_out;

    char* ws = (char*)d_ws;
    size_t off = 0;
    auto alloc = [&](size_t bytes) -> void* {
        void* p = ws + off;
        off += (bytes + 255) & ~(size_t)255;
        return p;
    };
    float* xt0p  = (float*)alloc((size_t)N0 * 128 * 4);
    __half* xt1h = (__half*)alloc((size_t)N0 * 128 * 2);
    __half* xt2h = (__half*)alloc((size_t)N0 * 576 * 2);
    float* yb    = (float*)alloc((size_t)N1 * 32 * 4);
    int* counts = (int*)alloc((N0 + N1 + N2) * 4);
    int* offs0 = (int*)alloc((N0 + 1) * 4);
    int* offs1 = (int*)alloc((N1 + 1) * 4);
    int* offs2 = (int*)alloc((N2 + 1) * 4);
    int* cur0 = (int*)alloc(N0 * 4);
    int* cur1 = (int*)alloc(N1 * 4);
    int* cur2 = (int*)alloc(N2 * 4);
    int* ss0 = (int*)alloc(E0C * 4);
    int* ss1 = (int*)alloc(E1C * 4);
    int* ss2 = (int*)alloc(E2C * 4);

    int etot = E0C + E1C + E2C;
    hipMemsetAsync(counts, 0, (size_t)(N0 + N1 + N2) * 4, stream);
    hist_all<<<(etot + 255) / 256, 256, 0, stream>>>(ei0, ei1, ei2, counts);
    scan_all<<<3, 1024, 0, stream>>>(counts, offs0, cur0, offs1, cur1, offs2, cur2);
    scatter_all<<<(etot + 255) / 256, 256, 0, stream>>>(ei0, ei1, ei2, cur0, cur1, cur2, ss0, ss1, ss2);
    gather_kernel<<<(N0 * 16 + 255) / 256, 256, 0, stream>>>(x, n_id, xt0p);
    sage1_kernel<<<N0 / 4, 256, 0, stream>>>(xt0p, offs0, ss0, W1, b1, xt1h);
    sage2_kernel<<<N0 / 4, 256, 0, stream>>>(xt1h, offs0, ss0, W2, b2, xt2h);
    sage3_kernel<<<N1, 256, 0, stream>>>(xt2h, offs1, ss1, W3, b3, W4, yb);
    final_kernel<<<(N2 * 16 + 255) / 256, 256, 0, stream>>>(yb, offs2, ss2, b4, out);
}

// Round 7
// 188.676 us; speedup vs baseline: 1.1018x; 1.1018x over previous
//
#include <hip/hip_runtime.h>
#include <hip/hip_fp16.h>

#define NTOT 50000
#define N0 20000
#define N1 5000
#define N2 1000
#define E0C 320000
#define E1C 80000
#define E2C 16000

typedef _Float16 half8 __attribute__((ext_vector_type(8)));
typedef float floatx4 __attribute__((ext_vector_type(4)));

__global__ void hist_all(const int* __restrict__ ei0, const int* __restrict__ ei1,
                         const int* __restrict__ ei2, int* __restrict__ counts) {
    int i = blockIdx.x * blockDim.x + threadIdx.x;
    if (i < E0C) {
        atomicAdd(&counts[ei0[E0C + i]], 1);
    } else if (i < E0C + E1C) {
        int j = i - E0C;
        atomicAdd(&counts[N0 + ei1[E1C + j]], 1);
    } else if (i < E0C + E1C + E2C) {
        int j = i - E0C - E1C;
        atomicAdd(&counts[N0 + N1 + ei2[E2C + j]], 1);
    }
}

__global__ __launch_bounds__(1024) void scan_all(
    const int* __restrict__ counts,
    int* __restrict__ offs0, int* __restrict__ cur0,
    int* __restrict__ offs1, int* __restrict__ cur1,
    int* __restrict__ offs2, int* __restrict__ cur2) {
    int g = blockIdx.x;
    int n = (g == 0) ? N0 : (g == 1) ? N1 : N2;
    const int* cnt = counts + ((g == 0) ? 0 : (g == 1) ? N0 : N0 + N1);
    int* offs = (g == 0) ? offs0 : (g == 1) ? offs1 : offs2;
    int* cur  = (g == 0) ? cur0  : (g == 1) ? cur1  : cur2;
    int t = threadIdx.x;
    int chunk = (n + 1023) >> 10;
    int lo = t * chunk;
    int hi = min(lo + chunk, n);
    int s = 0;
    for (int i = lo; i < hi; i++) s += cnt[i];
    int lane = t & 63, wid = t >> 6;
    int v = s;
    for (int d = 1; d < 64; d <<= 1) {
        int u = __shfl_up(v, d, 64);
        if (lane >= d) v += u;
    }
    __shared__ int wsum[16];
    __shared__ int woff[16];
    if (lane == 63) wsum[wid] = v;
    __syncthreads();
    if (t < 16) {
        int wv = wsum[t];
        int iv = wv;
        for (int d = 1; d < 16; d <<= 1) {
            int u = __shfl_up(iv, d, 64);
            if (t >= d) iv += u;
        }
        woff[t] = iv - wv;
    }
    __syncthreads();
    int run = woff[wid] + v - s;
    for (int i = lo; i < hi; i++) {
        offs[i] = run;
        cur[i] = run;
        run += cnt[i];
    }
    if (lo < n && hi == n) offs[n] = run;
}

__global__ void scatter_all(const int* __restrict__ ei0, const int* __restrict__ ei1,
                            const int* __restrict__ ei2,
                            int* __restrict__ cur0, int* __restrict__ cur1, int* __restrict__ cur2,
                            int* __restrict__ ss0, int* __restrict__ ss1, int* __restrict__ ss2) {
    int i = blockIdx.x * blockDim.x + threadIdx.x;
    if (i < E0C) {
        int d = ei0[E0C + i];
        int pos = atomicAdd(&cur0[d], 1);
        ss0[pos] = ei0[i];
    } else if (i < E0C + E1C) {
        int j = i - E0C;
        int d = ei1[E1C + j];
        int pos = atomicAdd(&cur1[d], 1);
        ss1[pos] = ei1[j];
    } else if (i < E0C + E1C + E2C) {
        int j = i - E0C - E1C;
        int d = ei2[E2C + j];
        int pos = atomicAdd(&cur2[d], 1);
        ss2[pos] = ei2[j];
    }
}

// xt0p[n][b][8] = x[b][n_id[n]][0..4] padded to 8 floats
__global__ void gather_kernel(const float* __restrict__ x, const int* __restrict__ n_id,
                              float* __restrict__ xt0p) {
    int idx = blockIdx.x * blockDim.x + threadIdx.x;
    if (idx >= N0 * 16) return;
    int n = idx >> 4, b = idx & 15;
    const float* p = x + (size_t)b * (NTOT * 5) + (size_t)n_id[n] * 5;
    float* q = xt0p + (size_t)n * 128 + b * 8;
    float4 v0 = {p[0], p[1], p[2], p[3]};
    float4 v1 = {p[4], 0.f, 0.f, 0.f};
    *(float4*)q = v0;
    *(float4*)(q + 4) = v1;
}

// W3 pre-swizzled into MFMA B-fragment order:
// W3B[((t*2+ks)*64 + lane)*8 + j] = W3[k][col], k=ks*32+(lane>>4)*8+j, col=t*16+(lane&15)
__global__ void prep_w3b(const float* __restrict__ W3, _Float16* __restrict__ W3B) {
    int idx = blockIdx.x * 256 + threadIdx.x;
    if (idx >= 14 * 2 * 64 * 8) return;
    int j = idx & 7;
    int l = (idx >> 3) & 63;
    int ks = (idx >> 9) & 1;
    int t = idx >> 10;
    int k = ks * 32 + (l >> 4) * 8 + j;
    int col = t * 16 + (l & 15);
    float v = (k < 36 && col < 216) ? W3[k * 216 + col] : 0.f;
    W3B[idx] = (_Float16)v;
}

// SAGE layer 1: quarter-wave per dst; fp32 in, fp16 out; edge loop unrolled x2
__global__ __launch_bounds__(256) void sage1_kernel(
    const float* __restrict__ xt0p, const int* __restrict__ offs, const int* __restrict__ ssrc,
    const float* __restrict__ W, const float* __restrict__ bias, __half* __restrict__ xt1h) {
    int gtid = blockIdx.x * blockDim.x + threadIdx.x;
    int wid = gtid >> 6;
    int lane = threadIdx.x & 63;
    int d = wid * 4 + (lane >> 4);
    int b = lane & 15;
    if (d >= N0) return;
    const float* ps = xt0p + (size_t)d * 128 + b * 8;
    float4 x0 = *(const float4*)ps;
    float x4 = ps[4];
    float xs[5] = {x0.x, x0.y, x0.z, x0.w, x4};
    float a[5] = {xs[0], xs[1], xs[2], xs[3], xs[4]};
    int e0 = offs[d], e1 = offs[d + 1];
    int e = e0;
    for (; e + 1 < e1; e += 2) {
        int s0 = ssrc[e], s1 = ssrc[e + 1];
        const float* p0 = xt0p + (size_t)s0 * 128 + b * 8;
        const float* p1 = xt0p + (size_t)s1 * 128 + b * 8;
        float4 v = *(const float4*)p0;
        float v4 = p0[4];
        float4 w = *(const float4*)p1;
        float w4 = p1[4];
        a[0] += v.x + w.x; a[1] += v.y + w.y; a[2] += v.z + w.z;
        a[3] += v.w + w.w; a[4] += v4 + w4;
    }
    if (e < e1) {
        const float* p = xt0p + (size_t)ssrc[e] * 128 + b * 8;
        float4 v = *(const float4*)p;
        float v4 = p[4];
        a[0] += v.x; a[1] += v.y; a[2] += v.z; a[3] += v.w; a[4] += v4;
    }
    float inv = 1.f / (float)(e1 - e0 + 1);
#pragma unroll
    for (int c = 0; c < 5; c++) a[c] *= inv;
    float o[6];
#pragma unroll
    for (int j = 0; j < 6; j++) {
        float acc = bias[j];
#pragma unroll
        for (int i = 0; i < 5; i++) acc += xs[i] * W[i * 6 + j];
#pragma unroll
        for (int i = 0; i < 5; i++) acc += a[i] * W[(5 + i) * 6 + j];
        o[j] = acc;
    }
    float nrm = 0.f;
#pragma unroll
    for (int j = 0; j < 6; j++) nrm += o[j] * o[j];
    float r = 1.f / fmaxf(sqrtf(nrm), 1e-12f);
    union { __half h[8]; uint4 u; } pk;
#pragma unroll
    for (int j = 0; j < 6; j++) pk.h[j] = __float2half_rn(fmaxf(o[j] * r, 0.f));
    pk.h[6] = __half(0.f);
    pk.h[7] = __half(0.f);
    *(uint4*)(xt1h + (size_t)d * 128 + b * 8) = pk.u;
}

// SAGE layer 2: quarter-wave per dst; fp16 in (1 b128/edge, unroll x2),
// writes xt2h TRANSPOSED fp16: xt2h[d][c][b] (c<36, b<16)
__global__ __launch_bounds__(256) void sage2_kernel(
    const __half* __restrict__ xt1h, const int* __restrict__ offs, const int* __restrict__ ssrc,
    const float* __restrict__ W, const float* __restrict__ bias, __half* __restrict__ xt2h) {
    int gtid = blockIdx.x * blockDim.x + threadIdx.x;
    int wid = gtid >> 6;
    int lane = threadIdx.x & 63;
    int d = wid * 4 + (lane >> 4);
    int b = lane & 15;
    if (d >= N0) return;
    const __half2* ps = (const __half2*)(xt1h + (size_t)d * 128 + b * 8);
    float2 s01 = __half22float2(ps[0]);
    float2 s23 = __half22float2(ps[1]);
    float2 s45 = __half22float2(ps[2]);
    float xs[6] = {s01.x, s01.y, s23.x, s23.y, s45.x, s45.y};
    float a[6] = {xs[0], xs[1], xs[2], xs[3], xs[4], xs[5]};
    int e0 = offs[d], e1 = offs[d + 1];
    int e = e0;
    union { uint4 u; __half2 h2[4]; } pk0, pk1;
    for (; e + 1 < e1; e += 2) {
        int s0 = ssrc[e], s1 = ssrc[e + 1];
        pk0.u = *(const uint4*)(xt1h + (size_t)s0 * 128 + b * 8);
        pk1.u = *(const uint4*)(xt1h + (size_t)s1 * 128 + b * 8);
        float2 v01 = __half22float2(pk0.h2[0]);
        float2 v23 = __half22float2(pk0.h2[1]);
        float2 v45 = __half22float2(pk0.h2[2]);
        float2 w01 = __half22float2(pk1.h2[0]);
        float2 w23 = __half22float2(pk1.h2[1]);
        float2 w45 = __half22float2(pk1.h2[2]);
        a[0] += v01.x + w01.x; a[1] += v01.y + w01.y; a[2] += v23.x + w23.x;
        a[3] += v23.y + w23.y; a[4] += v45.x + w45.x; a[5] += v45.y + w45.y;
    }
    if (e < e1) {
        pk0.u = *(const uint4*)(xt1h + (size_t)ssrc[e] * 128 + b * 8);
        float2 v01 = __half22float2(pk0.h2[0]);
        float2 v23 = __half22float2(pk0.h2[1]);
        float2 v45 = __half22float2(pk0.h2[2]);
        a[0] += v01.x; a[1] += v01.y; a[2] += v23.x;
        a[3] += v23.y; a[4] += v45.x; a[5] += v45.y;
    }
    float inv = 1.f / (float)(e1 - e0 + 1);
#pragma unroll
    for (int c = 0; c < 6; c++) a[c] *= inv;
    float o[36];
#pragma unroll
    for (int j = 0; j < 36; j++) {
        float acc = bias[j];
#pragma unroll
        for (int i = 0; i < 6; i++) acc += xs[i] * W[i * 36 + j];
#pragma unroll
        for (int i = 0; i < 6; i++) acc += a[i] * W[(6 + i) * 36 + j];
        o[j] = acc;
    }
    float nrm = 0.f;
#pragma unroll
    for (int j = 0; j < 36; j++) nrm += o[j] * o[j];
    float r = 1.f / fmaxf(sqrtf(nrm), 1e-12f);
    __half* pd = xt2h + (size_t)d * 576 + b;   // [d][c][b] layout, stride 16 per c
#pragma unroll
    for (int j = 0; j < 36; j++) pd[j * 16] = __float2half_rn(fmaxf(o[j] * r, 0.f));
}

// Fused layer-3: one 256-thread BLOCK per dst (4 waves).
// Phase A: 4 waves split edges (strided), fp32 partials -> LDS reduce into
//          sT[k*16+b] (K zero-padded to 64).
// Phase B: MFMA 16x16x32_f16. A-frag from sT (ds_read+cvt), B-frag = W3B
//          (pre-swizzled fragment order, coalesced 16B, L2-hot). Each wave owns
//          N-tiles {w, w+4, w+8, w+12}; epilogue relu+b3 then W4 projection on
//          C-frags, 4-step shfl reduce over cols, cross-wave LDS reduce.
__global__ __launch_bounds__(256) void sage3_kernel(
    const __half* __restrict__ xt2h, const int* __restrict__ offs, const int* __restrict__ ssrc,
    const _Float16* __restrict__ W3B, const float* __restrict__ b3,
    const float* __restrict__ W4, float* __restrict__ y) {
    __shared__ float sPart[4][576];
    __shared__ float sT[1024];       // [k][b], k<64 (zero-padded), b<16
    __shared__ float sRed[4][32];
    int t = threadIdx.x;
    int w = t >> 6, q = t & 63;
    int d = blockIdx.x;
    int e0 = offs[d], e1 = offs[d + 1];

    // phase A: strided 4-way edge split
    float acc[16];
#pragma unroll
    for (int i = 0; i < 16; i++) acc[i] = 0.f;
    const uint4* base = (const uint4*)xt2h;   // node row = 72 uint4 (1152B)
    union { uint4 u; __half2 h2[4]; } c0;
    for (int e = e0 + w; e < e1; e += 4) {
        const uint4* p0 = base + (size_t)ssrc[e] * 72;
        c0.u = p0[q];
#pragma unroll
        for (int j = 0; j < 4; j++) {
            float2 f = __half22float2(c0.h2[j]);
            acc[2 * j] += f.x;
            acc[2 * j + 1] += f.y;
        }
        if (q < 8) {
            c0.u = p0[64 + q];
#pragma unroll
            for (int j = 0; j < 4; j++) {
                float2 f = __half22float2(c0.h2[j]);
                acc[8 + 2 * j] += f.x;
                acc[9 + 2 * j] += f.y;
            }
        }
    }
#pragma unroll
    for (int j = 0; j < 8; j++) sPart[w][q * 8 + j] = acc[j];
    if (q < 8) {
#pragma unroll
        for (int j = 0; j < 8; j++) sPart[w][512 + q * 8 + j] = acc[8 + j];
    }
    __syncthreads();
    float inv = 1.f / fmaxf((float)(e1 - e0), 1.f);
    for (int i = t; i < 1024; i += 256)
        sT[i] = (i < 576) ? (sPart[0][i] + sPart[1][i] + sPart[2][i] + sPart[3][i]) * inv : 0.f;
    __syncthreads();

    // phase B: MFMA
    int lb = q & 15;    // A row (batch b) / B,C col-within-tile
    int hg = q >> 4;    // k/row group
    half8 aF[2];
#pragma unroll
    for (int ks = 0; ks < 2; ks++) {
#pragma unroll
        for (int j = 0; j < 8; j++) {
            int k = ks * 32 + hg * 8 + j;
            aF[ks][j] = (_Float16)sT[k * 16 + lb];
        }
    }
    float y0[4] = {0.f, 0.f, 0.f, 0.f};
    float y1[4] = {0.f, 0.f, 0.f, 0.f};
#pragma unroll
    for (int tt = 0; tt < 4; tt++) {
        int tile = w + 4 * tt;
        if (tile >= 14) break;
        floatx4 cacc = {0.f, 0.f, 0.f, 0.f};
#pragma unroll
        for (int ks = 0; ks < 2; ks++) {
            half8 bF = *(const half8*)(W3B + ((size_t)(tile * 2 + ks) * 64 + q) * 8);
            cacc = __builtin_amdgcn_mfma_f32_16x16x32_f16(aF[ks], bF, cacc, 0, 0, 0);
        }
        int col = tile * 16 + lb;
        float bj  = (col < 216) ? b3[col] : 0.f;
        float w40 = (col < 216) ? W4[col * 2] : 0.f;
        float w41 = (col < 216) ? W4[col * 2 + 1] : 0.f;
#pragma unroll
        for (int r = 0; r < 4; r++) {
            float vv = fmaxf(cacc[r] + bj, 0.f);
            y0[r] = fmaf(vv, w40, y0[r]);
            y1[r] = fmaf(vv, w41, y1[r]);
        }
    }
    // reduce over the 16 cols (lanes differing in lb)
#pragma unroll
    for (int m = 1; m <= 8; m <<= 1) {
#pragma unroll
        for (int r = 0; r < 4; r++) {
            y0[r] += __shfl_xor(y0[r], m, 64);
            y1[r] += __shfl_xor(y1[r], m, 64);
        }
    }
    if (lb == 0) {
#pragma unroll
        for (int r = 0; r < 4; r++) {
            int row = hg * 4 + r;             // batch index
            sRed[w][row * 2 + 0] = y0[r];
            sRed[w][row * 2 + 1] = y1[r];
        }
    }
    __syncthreads();
    if (t < 32) y[(size_t)d * 32 + t] = sRed[0][t] + sRed[1][t] + sRed[2][t] + sRed[3][t];
}

// layer 4: mean-agg of projected y over edges2, + b4. out[b][n][k].
__global__ void final_kernel(const float* __restrict__ y, const int* __restrict__ offs,
                             const int* __restrict__ ssrc, const float* __restrict__ b4,
                             float* __restrict__ out) {
    int idx = blockIdx.x * blockDim.x + threadIdx.x;
    if (idx >= N2 * 16) return;
    int d = idx >> 4, b = idx & 15;
    int e0 = offs[d], e1 = offs[d + 1];
    float s0 = 0.f, s1 = 0.f;
    for (int e = e0; e < e1; e++) {
        int s = ssrc[e];
        const float2 v = *(const float2*)(y + (size_t)s * 32 + b * 2);
        s0 += v.x; s1 += v.y;
    }
    float inv = 1.f / fmaxf((float)(e1 - e0), 1.f);
    out[b * (N2 * 2) + d * 2 + 0] = s0 * inv + b4[0];
    out[b * (N2 * 2) + d * 2 + 1] = s1 * inv + b4[1];
}

extern "C" void kernel_launch(void* const* d_in, const int* in_sizes, int n_in,
                              void* d_out, int out_size, void* d_ws, size_t ws_size,
                              hipStream_t stream) {
    const float* x   = (const float*)d_in[0];
    const int* n_id  = (const int*)d_in[1];
    const int* ei0   = (const int*)d_in[2];
    const int* ei1   = (const int*)d_in[3];
    const int* ei2   = (const int*)d_in[4];
    const float* W1  = (const float*)d_in[5];
    const float* b1  = (const float*)d_in[6];
    const float* W2  = (const float*)d_in[7];
    const float* b2  = (const float*)d_in[8];
    const float* W3  = (const float*)d_in[9];
    const float* b3  = (const float*)d_in[10];
    const float* W4  = (const float*)d_in[11];
    const float* b4  = (const float*)d_in[12];
    float* out = (float*)d_out;

    char* ws = (char*)d_ws;
    size_t off = 0;
    auto alloc = [&](size_t bytes) -> void* {
        void* p = ws + off;
        off += (bytes + 255) & ~(size_t)255;
        return p;
    };
    float* xt0p  = (float*)alloc((size_t)N0 * 128 * 4);
    __half* xt1h = (__half*)alloc((size_t)N0 * 128 * 2);
    __half* xt2h = (__half*)alloc((size_t)N0 * 576 * 2);
    float* yb    = (float*)alloc((size_t)N1 * 32 * 4);
    _Float16* W3B = (_Float16*)alloc((size_t)14 * 2 * 64 * 8 * 2);
    int* counts = (int*)alloc((N0 + N1 + N2) * 4);
    int* offs0 = (int*)alloc((N0 + 1) * 4);
    int* offs1 = (int*)alloc((N1 + 1) * 4);
    int* offs2 = (int*)alloc((N2 + 1) * 4);
    int* cur0 = (int*)alloc(N0 * 4);
    int* cur1 = (int*)alloc(N1 * 4);
    int* cur2 = (int*)alloc(N2 * 4);
    int* ss0 = (int*)alloc(E0C * 4);
    int* ss1 = (int*)alloc(E1C * 4);
    int* ss2 = (int*)alloc(E2C * 4);

    int etot = E0C + E1C + E2C;
    hipMemsetAsync(counts, 0, (size_t)(N0 + N1 + N2) * 4, stream);
    prep_w3b<<<56, 256, 0, stream>>>(W3, W3B);
    hist_all<<<(etot + 255) / 256, 256, 0, stream>>>(ei0, ei1, ei2, counts);
    scan_all<<<3, 1024, 0, stream>>>(counts, offs0, cur0, offs1, cur1, offs2, cur2);
    scatter_all<<<(etot + 255) / 256, 256, 0, stream>>>(ei0, ei1, ei2, cur0, cur1, cur2, ss0, ss1, ss2);
    gather_kernel<<<(N0 * 16 + 255) / 256, 256, 0, stream>>>(x, n_id, xt0p);
    sage1_kernel<<<N0 / 16, 256, 0, stream>>>(xt0p, offs0, ss0, W1, b1, xt1h);
    sage2_kernel<<<N0 / 16, 256, 0, stream>>>(xt1h, offs0, ss0, W2, b2, xt2h);
    sage3_kernel<<<N1, 256, 0, stream>>>(xt2h, offs1, ss1, W3B, b3, W4, yb);
    final_kernel<<<(N2 * 16 + 255) / 256, 256, 0, stream>>>(yb, offs2, ss2, b4, out);
}

// Round 8
// 186.722 us; speedup vs baseline: 1.1134x; 1.0105x over previous
//
#include <hip/hip_runtime.h>
#include <hip/hip_fp16.h>

#define NTOT 50000
#define N0 20000
#define N1 5000
#define N2 1000
#define E0C 320000
#define E1C 80000
#define E2C 16000

typedef _Float16 half8 __attribute__((ext_vector_type(8)));
typedef float floatx4 __attribute__((ext_vector_type(4)));

__global__ void zero_ints(int* __restrict__ p, int n) {
    int i = blockIdx.x * blockDim.x + threadIdx.x;
    if (i < n) p[i] = 0;
}

__global__ void hist_all(const int* __restrict__ ei0, const int* __restrict__ ei1,
                         const int* __restrict__ ei2, int* __restrict__ counts) {
    int i = blockIdx.x * blockDim.x + threadIdx.x;
    if (i < E0C) {
        atomicAdd(&counts[ei0[E0C + i]], 1);
    } else if (i < E0C + E1C) {
        int j = i - E0C;
        atomicAdd(&counts[N0 + ei1[E1C + j]], 1);
    } else if (i < E0C + E1C + E2C) {
        int j = i - E0C - E1C;
        atomicAdd(&counts[N0 + N1 + ei2[E2C + j]], 1);
    }
}

__global__ __launch_bounds__(1024) void scan_all(
    const int* __restrict__ counts,
    int* __restrict__ offs0, int* __restrict__ cur0,
    int* __restrict__ offs1, int* __restrict__ cur1,
    int* __restrict__ offs2, int* __restrict__ cur2) {
    int g = blockIdx.x;
    int n = (g == 0) ? N0 : (g == 1) ? N1 : N2;
    const int* cnt = counts + ((g == 0) ? 0 : (g == 1) ? N0 : N0 + N1);
    int* offs = (g == 0) ? offs0 : (g == 1) ? offs1 : offs2;
    int* cur  = (g == 0) ? cur0  : (g == 1) ? cur1  : cur2;
    int t = threadIdx.x;
    int chunk = (n + 1023) >> 10;
    int lo = t * chunk;
    int hi = min(lo + chunk, n);
    int s = 0;
    for (int i = lo; i < hi; i++) s += cnt[i];
    int lane = t & 63, wid = t >> 6;
    int v = s;
    for (int d = 1; d < 64; d <<= 1) {
        int u = __shfl_up(v, d, 64);
        if (lane >= d) v += u;
    }
    __shared__ int wsum[16];
    __shared__ int woff[16];
    if (lane == 63) wsum[wid] = v;
    __syncthreads();
    if (t < 16) {
        int wv = wsum[t];
        int iv = wv;
        for (int d = 1; d < 16; d <<= 1) {
            int u = __shfl_up(iv, d, 64);
            if (t >= d) iv += u;
        }
        woff[t] = iv - wv;
    }
    __syncthreads();
    int run = woff[wid] + v - s;
    for (int i = lo; i < hi; i++) {
        offs[i] = run;
        cur[i] = run;
        run += cnt[i];
    }
    if (lo < n && hi == n) offs[n] = run;
}

__global__ void scatter_all(const int* __restrict__ ei0, const int* __restrict__ ei1,
                            const int* __restrict__ ei2,
                            int* __restrict__ cur0, int* __restrict__ cur1, int* __restrict__ cur2,
                            int* __restrict__ ss0, int* __restrict__ ss1, int* __restrict__ ss2) {
    int i = blockIdx.x * blockDim.x + threadIdx.x;
    if (i < E0C) {
        int d = ei0[E0C + i];
        int pos = atomicAdd(&cur0[d], 1);
        ss0[pos] = ei0[i];
    } else if (i < E0C + E1C) {
        int j = i - E0C;
        int d = ei1[E1C + j];
        int pos = atomicAdd(&cur1[d], 1);
        ss1[pos] = ei1[j];
    } else if (i < E0C + E1C + E2C) {
        int j = i - E0C - E1C;
        int d = ei2[E2C + j];
        int pos = atomicAdd(&cur2[d], 1);
        ss2[pos] = ei2[j];
    }
}

// xt0p[n][b][8] = x[b][n_id[n]][0..4] padded to 8 floats
__global__ void gather_kernel(const float* __restrict__ x, const int* __restrict__ n_id,
                              float* __restrict__ xt0p) {
    int idx = blockIdx.x * blockDim.x + threadIdx.x;
    if (idx >= N0 * 16) return;
    int n = idx >> 4, b = idx & 15;
    const float* p = x + (size_t)b * (NTOT * 5) + (size_t)n_id[n] * 5;
    float* q = xt0p + (size_t)n * 128 + b * 8;
    float4 v0 = {p[0], p[1], p[2], p[3]};
    float4 v1 = {p[4], 0.f, 0.f, 0.f};
    *(float4*)q = v0;
    *(float4*)(q + 4) = v1;
}

// W3 pre-swizzled into MFMA B-fragment order:
// W3B[((t*2+ks)*64 + lane)*8 + j] = W3[k][col], k=ks*32+(lane>>4)*8+j, col=t*16+(lane&15)
__global__ void prep_w3b(const float* __restrict__ W3, _Float16* __restrict__ W3B) {
    int idx = blockIdx.x * 256 + threadIdx.x;
    if (idx >= 14 * 2 * 64 * 8) return;
    int j = idx & 7;
    int l = (idx >> 3) & 63;
    int ks = (idx >> 9) & 1;
    int t = idx >> 10;
    int k = ks * 32 + (l >> 4) * 8 + j;
    int col = t * 16 + (l & 15);
    float v = (k < 36 && col < 216) ? W3[k * 216 + col] : 0.f;
    W3B[idx] = (_Float16)v;
}

// SAGE layer 1: quarter-wave per dst; fp32 in, fp16 out; edge loop unrolled x4
__global__ __launch_bounds__(256) void sage1_kernel(
    const float* __restrict__ xt0p, const int* __restrict__ offs, const int* __restrict__ ssrc,
    const float* __restrict__ W, const float* __restrict__ bias, __half* __restrict__ xt1h) {
    int gtid = blockIdx.x * blockDim.x + threadIdx.x;
    int wid = gtid >> 6;
    int lane = threadIdx.x & 63;
    int d = wid * 4 + (lane >> 4);
    int b = lane & 15;
    if (d >= N0) return;
    const float* ps = xt0p + (size_t)d * 128 + b * 8;
    float4 x0 = *(const float4*)ps;
    float x4 = ps[4];
    float xs[5] = {x0.x, x0.y, x0.z, x0.w, x4};
    float a[5] = {xs[0], xs[1], xs[2], xs[3], xs[4]};
    int e0 = offs[d], e1 = offs[d + 1];
    int e = e0;
    for (; e + 3 < e1; e += 4) {
        const float* p0 = xt0p + (size_t)ssrc[e] * 128 + b * 8;
        const float* p1 = xt0p + (size_t)ssrc[e + 1] * 128 + b * 8;
        const float* p2 = xt0p + (size_t)ssrc[e + 2] * 128 + b * 8;
        const float* p3 = xt0p + (size_t)ssrc[e + 3] * 128 + b * 8;
        float4 v0 = *(const float4*)p0; float v04 = p0[4];
        float4 v1 = *(const float4*)p1; float v14 = p1[4];
        float4 v2 = *(const float4*)p2; float v24 = p2[4];
        float4 v3 = *(const float4*)p3; float v34 = p3[4];
        a[0] += (v0.x + v1.x) + (v2.x + v3.x);
        a[1] += (v0.y + v1.y) + (v2.y + v3.y);
        a[2] += (v0.z + v1.z) + (v2.z + v3.z);
        a[3] += (v0.w + v1.w) + (v2.w + v3.w);
        a[4] += (v04 + v14) + (v24 + v34);
    }
    for (; e < e1; e++) {
        const float* p = xt0p + (size_t)ssrc[e] * 128 + b * 8;
        float4 v = *(const float4*)p;
        float v4 = p[4];
        a[0] += v.x; a[1] += v.y; a[2] += v.z; a[3] += v.w; a[4] += v4;
    }
    float inv = 1.f / (float)(e1 - e0 + 1);
#pragma unroll
    for (int c = 0; c < 5; c++) a[c] *= inv;
    float o[6];
#pragma unroll
    for (int j = 0; j < 6; j++) {
        float acc = bias[j];
#pragma unroll
        for (int i = 0; i < 5; i++) acc += xs[i] * W[i * 6 + j];
#pragma unroll
        for (int i = 0; i < 5; i++) acc += a[i] * W[(5 + i) * 6 + j];
        o[j] = acc;
    }
    float nrm = 0.f;
#pragma unroll
    for (int j = 0; j < 6; j++) nrm += o[j] * o[j];
    float r = 1.f / fmaxf(sqrtf(nrm), 1e-12f);
    union { __half h[8]; uint4 u; } pk;
#pragma unroll
    for (int j = 0; j < 6; j++) pk.h[j] = __float2half_rn(fmaxf(o[j] * r, 0.f));
    pk.h[6] = __half(0.f);
    pk.h[7] = __half(0.f);
    *(uint4*)(xt1h + (size_t)d * 128 + b * 8) = pk.u;
}

// SAGE layer 2: quarter-wave per dst; fp16 in (1 b128/edge, unroll x4),
// writes xt2h TRANSPOSED fp16: xt2h[d][c][b] (c<36, b<16)
__global__ __launch_bounds__(256) void sage2_kernel(
    const __half* __restrict__ xt1h, const int* __restrict__ offs, const int* __restrict__ ssrc,
    const float* __restrict__ W, const float* __restrict__ bias, __half* __restrict__ xt2h) {
    int gtid = blockIdx.x * blockDim.x + threadIdx.x;
    int wid = gtid >> 6;
    int lane = threadIdx.x & 63;
    int d = wid * 4 + (lane >> 4);
    int b = lane & 15;
    if (d >= N0) return;
    const __half2* ps = (const __half2*)(xt1h + (size_t)d * 128 + b * 8);
    float2 s01 = __half22float2(ps[0]);
    float2 s23 = __half22float2(ps[1]);
    float2 s45 = __half22float2(ps[2]);
    float xs[6] = {s01.x, s01.y, s23.x, s23.y, s45.x, s45.y};
    float a[6] = {xs[0], xs[1], xs[2], xs[3], xs[4], xs[5]};
    int e0 = offs[d], e1 = offs[d + 1];
    int e = e0;
    union { uint4 u; __half2 h2[4]; } pk0, pk1, pk2, pk3;
    for (; e + 3 < e1; e += 4) {
        pk0.u = *(const uint4*)(xt1h + (size_t)ssrc[e] * 128 + b * 8);
        pk1.u = *(const uint4*)(xt1h + (size_t)ssrc[e + 1] * 128 + b * 8);
        pk2.u = *(const uint4*)(xt1h + (size_t)ssrc[e + 2] * 128 + b * 8);
        pk3.u = *(const uint4*)(xt1h + (size_t)ssrc[e + 3] * 128 + b * 8);
#pragma unroll
        for (int j = 0; j < 3; j++) {
            float2 v0 = __half22float2(pk0.h2[j]);
            float2 v1 = __half22float2(pk1.h2[j]);
            float2 v2 = __half22float2(pk2.h2[j]);
            float2 v3 = __half22float2(pk3.h2[j]);
            a[2 * j]     += (v0.x + v1.x) + (v2.x + v3.x);
            a[2 * j + 1] += (v0.y + v1.y) + (v2.y + v3.y);
        }
    }
    for (; e < e1; e++) {
        pk0.u = *(const uint4*)(xt1h + (size_t)ssrc[e] * 128 + b * 8);
#pragma unroll
        for (int j = 0; j < 3; j++) {
            float2 v0 = __half22float2(pk0.h2[j]);
            a[2 * j] += v0.x;
            a[2 * j + 1] += v0.y;
        }
    }
    float inv = 1.f / (float)(e1 - e0 + 1);
#pragma unroll
    for (int c = 0; c < 6; c++) a[c] *= inv;
    float o[36];
#pragma unroll
    for (int j = 0; j < 36; j++) {
        float acc = bias[j];
#pragma unroll
        for (int i = 0; i < 6; i++) acc += xs[i] * W[i * 36 + j];
#pragma unroll
        for (int i = 0; i < 6; i++) acc += a[i] * W[(6 + i) * 36 + j];
        o[j] = acc;
    }
    float nrm = 0.f;
#pragma unroll
    for (int j = 0; j < 36; j++) nrm += o[j] * o[j];
    float r = 1.f / fmaxf(sqrtf(nrm), 1e-12f);
    __half* pd = xt2h + (size_t)d * 576 + b;   // [d][c][b] layout, stride 16 per c
#pragma unroll
    for (int j = 0; j < 36; j++) pd[j * 16] = __float2half_rn(fmaxf(o[j] * r, 0.f));
}

// Fused layer-3: one 256-thread BLOCK per dst (4 waves).
// Phase A: 4 waves split edges (strided), fp32 partials -> LDS reduce into
//          sT[k*16+b] (K zero-padded to 64).
// Phase B: MFMA 16x16x32_f16. A-frag from sT (ds_read+cvt), B-frag = W3B
//          (pre-swizzled fragment order, coalesced 16B, L2-hot).
__global__ __launch_bounds__(256) void sage3_kernel(
    const __half* __restrict__ xt2h, const int* __restrict__ offs, const int* __restrict__ ssrc,
    const _Float16* __restrict__ W3B, const float* __restrict__ b3,
    const float* __restrict__ W4, float* __restrict__ y) {
    __shared__ float sPart[4][576];
    __shared__ float sT[1024];       // [k][b], k<64 (zero-padded), b<16
    __shared__ float sRed[4][32];
    int t = threadIdx.x;
    int w = t >> 6, q = t & 63;
    int d = blockIdx.x;
    int e0 = offs[d], e1 = offs[d + 1];

    // phase A: strided 4-way edge split
    float acc[16];
#pragma unroll
    for (int i = 0; i < 16; i++) acc[i] = 0.f;
    const uint4* base = (const uint4*)xt2h;   // node row = 72 uint4 (1152B)
    union { uint4 u; __half2 h2[4]; } c0;
    for (int e = e0 + w; e < e1; e += 4) {
        const uint4* p0 = base + (size_t)ssrc[e] * 72;
        c0.u = p0[q];
#pragma unroll
        for (int j = 0; j < 4; j++) {
            float2 f = __half22float2(c0.h2[j]);
            acc[2 * j] += f.x;
            acc[2 * j + 1] += f.y;
        }
        if (q < 8) {
            c0.u = p0[64 + q];
#pragma unroll
            for (int j = 0; j < 4; j++) {
                float2 f = __half22float2(c0.h2[j]);
                acc[8 + 2 * j] += f.x;
                acc[9 + 2 * j] += f.y;
            }
        }
    }
#pragma unroll
    for (int j = 0; j < 8; j++) sPart[w][q * 8 + j] = acc[j];
    if (q < 8) {
#pragma unroll
        for (int j = 0; j < 8; j++) sPart[w][512 + q * 8 + j] = acc[8 + j];
    }
    __syncthreads();
    float inv = 1.f / fmaxf((float)(e1 - e0), 1.f);
    for (int i = t; i < 1024; i += 256)
        sT[i] = (i < 576) ? (sPart[0][i] + sPart[1][i] + sPart[2][i] + sPart[3][i]) * inv : 0.f;
    __syncthreads();

    // phase B: MFMA
    int lb = q & 15;    // A row (batch b) / B,C col-within-tile
    int hg = q >> 4;    // k/row group
    half8 aF[2];
#pragma unroll
    for (int ks = 0; ks < 2; ks++) {
#pragma unroll
        for (int j = 0; j < 8; j++) {
            int k = ks * 32 + hg * 8 + j;
            aF[ks][j] = (_Float16)sT[k * 16 + lb];
        }
    }
    float y0[4] = {0.f, 0.f, 0.f, 0.f};
    float y1[4] = {0.f, 0.f, 0.f, 0.f};
#pragma unroll
    for (int tt = 0; tt < 4; tt++) {
        int tile = w + 4 * tt;
        if (tile >= 14) break;
        floatx4 cacc = {0.f, 0.f, 0.f, 0.f};
#pragma unroll
        for (int ks = 0; ks < 2; ks++) {
            half8 bF = *(const half8*)(W3B + ((size_t)(tile * 2 + ks) * 64 + q) * 8);
            cacc = __builtin_amdgcn_mfma_f32_16x16x32_f16(aF[ks], bF, cacc, 0, 0, 0);
        }
        int col = tile * 16 + lb;
        float bj  = (col < 216) ? b3[col] : 0.f;
        float w40 = (col < 216) ? W4[col * 2] : 0.f;
        float w41 = (col < 216) ? W4[col * 2 + 1] : 0.f;
#pragma unroll
        for (int r = 0; r < 4; r++) {
            float vv = fmaxf(cacc[r] + bj, 0.f);
            y0[r] = fmaf(vv, w40, y0[r]);
            y1[r] = fmaf(vv, w41, y1[r]);
        }
    }
    // reduce over the 16 cols (lanes differing in lb)
#pragma unroll
    for (int m = 1; m <= 8; m <<= 1) {
#pragma unroll
        for (int r = 0; r < 4; r++) {
            y0[r] += __shfl_xor(y0[r], m, 64);
            y1[r] += __shfl_xor(y1[r], m, 64);
        }
    }
    if (lb == 0) {
#pragma unroll
        for (int r = 0; r < 4; r++) {
            int row = hg * 4 + r;             // batch index
            sRed[w][row * 2 + 0] = y0[r];
            sRed[w][row * 2 + 1] = y1[r];
        }
    }
    __syncthreads();
    if (t < 32) y[(size_t)d * 32 + t] = sRed[0][t] + sRed[1][t] + sRed[2][t] + sRed[3][t];
}

// layer 4: mean-agg of projected y over edges2, + b4. out[b][n][k].
__global__ void final_kernel(const float* __restrict__ y, const int* __restrict__ offs,
                             const int* __restrict__ ssrc, const float* __restrict__ b4,
                             float* __restrict__ out) {
    int idx = blockIdx.x * blockDim.x + threadIdx.x;
    if (idx >= N2 * 16) return;
    int d = idx >> 4, b = idx & 15;
    int e0 = offs[d], e1 = offs[d + 1];
    float s0 = 0.f, s1 = 0.f;
    for (int e = e0; e < e1; e++) {
        int s = ssrc[e];
        const float2 v = *(const float2*)(y + (size_t)s * 32 + b * 2);
        s0 += v.x; s1 += v.y;
    }
    float inv = 1.f / fmaxf((float)(e1 - e0), 1.f);
    out[b * (N2 * 2) + d * 2 + 0] = s0 * inv + b4[0];
    out[b * (N2 * 2) + d * 2 + 1] = s1 * inv + b4[1];
}

extern "C" void kernel_launch(void* const* d_in, const int* in_sizes, int n_in,
                              void* d_out, int out_size, void* d_ws, size_t ws_size,
                              hipStream_t stream) {
    const float* x   = (const float*)d_in[0];
    const int* n_id  = (const int*)d_in[1];
    const int* ei0   = (const int*)d_in[2];
    const int* ei1   = (const int*)d_in[3];
    const int* ei2   = (const int*)d_in[4];
    const float* W1  = (const float*)d_in[5];
    const float* b1  = (const float*)d_in[6];
    const float* W2  = (const float*)d_in[7];
    const float* b2  = (const float*)d_in[8];
    const float* W3  = (const float*)d_in[9];
    const float* b3  = (const float*)d_in[10];
    const float* W4  = (const float*)d_in[11];
    const float* b4  = (const float*)d_in[12];
    float* out = (float*)d_out;

    char* ws = (char*)d_ws;
    size_t off = 0;
    auto alloc = [&](size_t bytes) -> void* {
        void* p = ws + off;
        off += (bytes + 255) & ~(size_t)255;
        return p;
    };
    float* xt0p  = (float*)alloc((size_t)N0 * 128 * 4);
    __half* xt1h = (__half*)alloc((size_t)N0 * 128 * 2);
    __half* xt2h = (__half*)alloc((size_t)N0 * 576 * 2);
    float* yb    = (float*)alloc((size_t)N1 * 32 * 4);
    _Float16* W3B = (_Float16*)alloc((size_t)14 * 2 * 64 * 8 * 2);
    int* counts = (int*)alloc((N0 + N1 + N2) * 4);
    int* offs0 = (int*)alloc((N0 + 1) * 4);
    int* offs1 = (int*)alloc((N1 + 1) * 4);
    int* offs2 = (int*)alloc((N2 + 1) * 4);
    int* cur0 = (int*)alloc(N0 * 4);
    int* cur1 = (int*)alloc(N1 * 4);
    int* cur2 = (int*)alloc(N2 * 4);
    int* ss0 = (int*)alloc(E0C * 4);
    int* ss1 = (int*)alloc(E1C * 4);
    int* ss2 = (int*)alloc(E2C * 4);

    int etot = E0C + E1C + E2C;
    zero_ints<<<(N0 + N1 + N2 + 255) / 256, 256, 0, stream>>>(counts, N0 + N1 + N2);
    prep_w3b<<<56, 256, 0, stream>>>(W3, W3B);
    hist_all<<<(etot + 255) / 256, 256, 0, stream>>>(ei0, ei1, ei2, counts);
    scan_all<<<3, 1024, 0, stream>>>(counts, offs0, cur0, offs1, cur1, offs2, cur2);
    scatter_all<<<(etot + 255) / 256, 256, 0, stream>>>(ei0, ei1, ei2, cur0, cur1, cur2, ss0, ss1, ss2);
    gather_kernel<<<(N0 * 16 + 255) / 256, 256, 0, stream>>>(x, n_id, xt0p);
    sage1_kernel<<<N0 / 16, 256, 0, stream>>>(xt0p, offs0, ss0, W1, b1, xt1h);
    sage2_kernel<<<N0 / 16, 256, 0, stream>>>(xt1h, offs0, ss0, W2, b2, xt2h);
    sage3_kernel<<<N1, 256, 0, stream>>>(xt2h, offs1, ss1, W3B, b3, W4, yb);
    final_kernel<<<(N2 * 16 + 255) / 256, 256, 0, stream>>>(yb, offs2, ss2, b4, out);
}

// Round 9
// 172.421 us; speedup vs baseline: 1.2057x; 1.0829x over previous
//
#include <hip/hip_runtime.h>
#include <hip/hip_fp16.h>

#define NTOT 50000
#define N0 20000
#define N1 5000
#define N2 1000
#define E0C 320000
#define E1C 80000
#define E2C 16000

#define ZERO_BLOCKS ((N0 + N1 + N2 + 255) / 256)
#define PREP_BLOCKS 56
#define HIST_BLOCKS ((E0C + E1C + E2C + 255) / 256)
#define GATH_BLOCKS ((N0 * 16 + 255) / 256)

typedef _Float16 half8 __attribute__((ext_vector_type(8)));
typedef float floatx4 __attribute__((ext_vector_type(4)));

// fused: zero counts  +  W3 pre-swizzle into MFMA B-fragment order
__global__ void init_kernel(int* __restrict__ counts, const float* __restrict__ W3,
                            _Float16* __restrict__ W3B) {
    int blk = blockIdx.x;
    if (blk < ZERO_BLOCKS) {
        int i = blk * 256 + threadIdx.x;
        if (i < N0 + N1 + N2) counts[i] = 0;
    } else {
        int idx = (blk - ZERO_BLOCKS) * 256 + threadIdx.x;
        if (idx < 14 * 2 * 64 * 8) {
            int j = idx & 7;
            int l = (idx >> 3) & 63;
            int ks = (idx >> 9) & 1;
            int t = idx >> 10;
            int k = ks * 32 + (l >> 4) * 8 + j;
            int col = t * 16 + (l & 15);
            float v = (k < 36 && col < 216) ? W3[k * 216 + col] : 0.f;
            W3B[idx] = (_Float16)v;
        }
    }
}

// fused: histogram over all 3 graphs  +  x gather->fp16 node-major
// xt0h[n][b][8] = fp16(x[b][n_id[n]][0..4]) padded to 8
__global__ void hist_gather(const int* __restrict__ ei0, const int* __restrict__ ei1,
                            const int* __restrict__ ei2, int* __restrict__ counts,
                            const float* __restrict__ x, const int* __restrict__ n_id,
                            __half* __restrict__ xt0h) {
    int blk = blockIdx.x;
    if (blk < HIST_BLOCKS) {
        int i = blk * 256 + threadIdx.x;
        if (i < E0C) {
            atomicAdd(&counts[ei0[E0C + i]], 1);
        } else if (i < E0C + E1C) {
            int j = i - E0C;
            atomicAdd(&counts[N0 + ei1[E1C + j]], 1);
        } else if (i < E0C + E1C + E2C) {
            int j = i - E0C - E1C;
            atomicAdd(&counts[N0 + N1 + ei2[E2C + j]], 1);
        }
    } else {
        int idx = (blk - HIST_BLOCKS) * 256 + threadIdx.x;
        if (idx < N0 * 16) {
            int n = idx >> 4, b = idx & 15;
            const float* p = x + (size_t)b * (NTOT * 5) + (size_t)n_id[n] * 5;
            union { __half h[8]; uint4 u; } pk;
#pragma unroll
            for (int c = 0; c < 5; c++) pk.h[c] = __float2half_rn(p[c]);
            pk.h[5] = __half(0.f);
            pk.h[6] = __half(0.f);
            pk.h[7] = __half(0.f);
            *(uint4*)(xt0h + (size_t)n * 128 + b * 8) = pk.u;
        }
    }
}

__global__ __launch_bounds__(1024) void scan_all(
    const int* __restrict__ counts,
    int* __restrict__ offs0, int* __restrict__ cur0,
    int* __restrict__ offs1, int* __restrict__ cur1,
    int* __restrict__ offs2, int* __restrict__ cur2) {
    int g = blockIdx.x;
    int n = (g == 0) ? N0 : (g == 1) ? N1 : N2;
    const int* cnt = counts + ((g == 0) ? 0 : (g == 1) ? N0 : N0 + N1);
    int* offs = (g == 0) ? offs0 : (g == 1) ? offs1 : offs2;
    int* cur  = (g == 0) ? cur0  : (g == 1) ? cur1  : cur2;
    int t = threadIdx.x;
    int chunk = (n + 1023) >> 10;
    int lo = t * chunk;
    int hi = min(lo + chunk, n);
    int s = 0;
    for (int i = lo; i < hi; i++) s += cnt[i];
    int lane = t & 63, wid = t >> 6;
    int v = s;
    for (int d = 1; d < 64; d <<= 1) {
        int u = __shfl_up(v, d, 64);
        if (lane >= d) v += u;
    }
    __shared__ int wsum[16];
    __shared__ int woff[16];
    if (lane == 63) wsum[wid] = v;
    __syncthreads();
    if (t < 16) {
        int wv = wsum[t];
        int iv = wv;
        for (int d = 1; d < 16; d <<= 1) {
            int u = __shfl_up(iv, d, 64);
            if (t >= d) iv += u;
        }
        woff[t] = iv - wv;
    }
    __syncthreads();
    int run = woff[wid] + v - s;
    for (int i = lo; i < hi; i++) {
        offs[i] = run;
        cur[i] = run;
        run += cnt[i];
    }
    if (lo < n && hi == n) offs[n] = run;
}

__global__ void scatter_all(const int* __restrict__ ei0, const int* __restrict__ ei1,
                            const int* __restrict__ ei2,
                            int* __restrict__ cur0, int* __restrict__ cur1, int* __restrict__ cur2,
                            int* __restrict__ ss0, int* __restrict__ ss1, int* __restrict__ ss2) {
    int i = blockIdx.x * blockDim.x + threadIdx.x;
    if (i < E0C) {
        int d = ei0[E0C + i];
        int pos = atomicAdd(&cur0[d], 1);
        ss0[pos] = ei0[i];
    } else if (i < E0C + E1C) {
        int j = i - E0C;
        int d = ei1[E1C + j];
        int pos = atomicAdd(&cur1[d], 1);
        ss1[pos] = ei1[j];
    } else if (i < E0C + E1C + E2C) {
        int j = i - E0C - E1C;
        int d = ei2[E2C + j];
        int pos = atomicAdd(&cur2[d], 1);
        ss2[pos] = ei2[j];
    }
}

// SAGE layer 1: quarter-wave per dst; fp16 in (1 uint4/edge), fp16 out; unroll x4
__global__ __launch_bounds__(256) void sage1_kernel(
    const __half* __restrict__ xt0h, const int* __restrict__ offs, const int* __restrict__ ssrc,
    const float* __restrict__ W, const float* __restrict__ bias, __half* __restrict__ xt1h) {
    int gtid = blockIdx.x * blockDim.x + threadIdx.x;
    int wid = gtid >> 6;
    int lane = threadIdx.x & 63;
    int d = wid * 4 + (lane >> 4);
    int b = lane & 15;
    if (d >= N0) return;
    union { uint4 u; __half2 h2[4]; } sp;
    sp.u = *(const uint4*)(xt0h + (size_t)d * 128 + b * 8);
    float2 s01 = __half22float2(sp.h2[0]);
    float2 s23 = __half22float2(sp.h2[1]);
    float2 s4x = __half22float2(sp.h2[2]);
    float xs[5] = {s01.x, s01.y, s23.x, s23.y, s4x.x};
    float a[5] = {xs[0], xs[1], xs[2], xs[3], xs[4]};
    int e0 = offs[d], e1 = offs[d + 1];
    int e = e0;
    union { uint4 u; __half2 h2[4]; } pk0, pk1, pk2, pk3;
    for (; e + 3 < e1; e += 4) {
        pk0.u = *(const uint4*)(xt0h + (size_t)ssrc[e] * 128 + b * 8);
        pk1.u = *(const uint4*)(xt0h + (size_t)ssrc[e + 1] * 128 + b * 8);
        pk2.u = *(const uint4*)(xt0h + (size_t)ssrc[e + 2] * 128 + b * 8);
        pk3.u = *(const uint4*)(xt0h + (size_t)ssrc[e + 3] * 128 + b * 8);
#pragma unroll
        for (int j = 0; j < 2; j++) {
            float2 v0 = __half22float2(pk0.h2[j]);
            float2 v1 = __half22float2(pk1.h2[j]);
            float2 v2 = __half22float2(pk2.h2[j]);
            float2 v3 = __half22float2(pk3.h2[j]);
            a[2 * j]     += (v0.x + v1.x) + (v2.x + v3.x);
            a[2 * j + 1] += (v0.y + v1.y) + (v2.y + v3.y);
        }
        float2 w0 = __half22float2(pk0.h2[2]);
        float2 w1 = __half22float2(pk1.h2[2]);
        float2 w2 = __half22float2(pk2.h2[2]);
        float2 w3 = __half22float2(pk3.h2[2]);
        a[4] += (w0.x + w1.x) + (w2.x + w3.x);
    }
    for (; e < e1; e++) {
        pk0.u = *(const uint4*)(xt0h + (size_t)ssrc[e] * 128 + b * 8);
        float2 v01 = __half22float2(pk0.h2[0]);
        float2 v23 = __half22float2(pk0.h2[1]);
        float2 v4x = __half22float2(pk0.h2[2]);
        a[0] += v01.x; a[1] += v01.y; a[2] += v23.x; a[3] += v23.y; a[4] += v4x.x;
    }
    float inv = 1.f / (float)(e1 - e0 + 1);
#pragma unroll
    for (int c = 0; c < 5; c++) a[c] *= inv;
    float o[6];
#pragma unroll
    for (int j = 0; j < 6; j++) {
        float acc = bias[j];
#pragma unroll
        for (int i = 0; i < 5; i++) acc += xs[i] * W[i * 6 + j];
#pragma unroll
        for (int i = 0; i < 5; i++) acc += a[i] * W[(5 + i) * 6 + j];
        o[j] = acc;
    }
    float nrm = 0.f;
#pragma unroll
    for (int j = 0; j < 6; j++) nrm += o[j] * o[j];
    float r = 1.f / fmaxf(sqrtf(nrm), 1e-12f);
    union { __half h[8]; uint4 u; } pk;
#pragma unroll
    for (int j = 0; j < 6; j++) pk.h[j] = __float2half_rn(fmaxf(o[j] * r, 0.f));
    pk.h[6] = __half(0.f);
    pk.h[7] = __half(0.f);
    *(uint4*)(xt1h + (size_t)d * 128 + b * 8) = pk.u;
}

// SAGE layer 2: quarter-wave per dst; fp16 in (1 uint4/edge, unroll x4),
// writes xt2h TRANSPOSED fp16: xt2h[d][c][b] (c<36, b<16)
__global__ __launch_bounds__(256) void sage2_kernel(
    const __half* __restrict__ xt1h, const int* __restrict__ offs, const int* __restrict__ ssrc,
    const float* __restrict__ W, const float* __restrict__ bias, __half* __restrict__ xt2h) {
    int gtid = blockIdx.x * blockDim.x + threadIdx.x;
    int wid = gtid >> 6;
    int lane = threadIdx.x & 63;
    int d = wid * 4 + (lane >> 4);
    int b = lane & 15;
    if (d >= N0) return;
    const __half2* ps = (const __half2*)(xt1h + (size_t)d * 128 + b * 8);
    float2 s01 = __half22float2(ps[0]);
    float2 s23 = __half22float2(ps[1]);
    float2 s45 = __half22float2(ps[2]);
    float xs[6] = {s01.x, s01.y, s23.x, s23.y, s45.x, s45.y};
    float a[6] = {xs[0], xs[1], xs[2], xs[3], xs[4], xs[5]};
    int e0 = offs[d], e1 = offs[d + 1];
    int e = e0;
    union { uint4 u; __half2 h2[4]; } pk0, pk1, pk2, pk3;
    for (; e + 3 < e1; e += 4) {
        pk0.u = *(const uint4*)(xt1h + (size_t)ssrc[e] * 128 + b * 8);
        pk1.u = *(const uint4*)(xt1h + (size_t)ssrc[e + 1] * 128 + b * 8);
        pk2.u = *(const uint4*)(xt1h + (size_t)ssrc[e + 2] * 128 + b * 8);
        pk3.u = *(const uint4*)(xt1h + (size_t)ssrc[e + 3] * 128 + b * 8);
#pragma unroll
        for (int j = 0; j < 3; j++) {
            float2 v0 = __half22float2(pk0.h2[j]);
            float2 v1 = __half22float2(pk1.h2[j]);
            float2 v2 = __half22float2(pk2.h2[j]);
            float2 v3 = __half22float2(pk3.h2[j]);
            a[2 * j]     += (v0.x + v1.x) + (v2.x + v3.x);
            a[2 * j + 1] += (v0.y + v1.y) + (v2.y + v3.y);
        }
    }
    for (; e < e1; e++) {
        pk0.u = *(const uint4*)(xt1h + (size_t)ssrc[e] * 128 + b * 8);
#pragma unroll
        for (int j = 0; j < 3; j++) {
            float2 v0 = __half22float2(pk0.h2[j]);
            a[2 * j] += v0.x;
            a[2 * j + 1] += v0.y;
        }
    }
    float inv = 1.f / (float)(e1 - e0 + 1);
#pragma unroll
    for (int c = 0; c < 6; c++) a[c] *= inv;
    float o[36];
#pragma unroll
    for (int j = 0; j < 36; j++) {
        float acc = bias[j];
#pragma unroll
        for (int i = 0; i < 6; i++) acc += xs[i] * W[i * 36 + j];
#pragma unroll
        for (int i = 0; i < 6; i++) acc += a[i] * W[(6 + i) * 36 + j];
        o[j] = acc;
    }
    float nrm = 0.f;
#pragma unroll
    for (int j = 0; j < 36; j++) nrm += o[j] * o[j];
    float r = 1.f / fmaxf(sqrtf(nrm), 1e-12f);
    __half* pd = xt2h + (size_t)d * 576 + b;   // [d][c][b] layout, stride 16 per c
#pragma unroll
    for (int j = 0; j < 36; j++) pd[j * 16] = __float2half_rn(fmaxf(o[j] * r, 0.f));
}

// Fused layer-3: one 256-thread BLOCK per dst (4 waves).
// Phase A: 4 waves split edges (strided), fp32 partials -> LDS reduce into
//          sT[k*16+b] (K zero-padded to 64).
// Phase B: MFMA 16x16x32_f16. A-frag from sT, B-frag = W3B (pre-swizzled).
__global__ __launch_bounds__(256) void sage3_kernel(
    const __half* __restrict__ xt2h, const int* __restrict__ offs, const int* __restrict__ ssrc,
    const _Float16* __restrict__ W3B, const float* __restrict__ b3,
    const float* __restrict__ W4, float* __restrict__ y) {
    __shared__ float sPart[4][576];
    __shared__ float sT[1024];       // [k][b], k<64 (zero-padded), b<16
    __shared__ float sRed[4][32];
    int t = threadIdx.x;
    int w = t >> 6, q = t & 63;
    int d = blockIdx.x;
    int e0 = offs[d], e1 = offs[d + 1];

    // phase A: strided 4-way edge split
    float acc[16];
#pragma unroll
    for (int i = 0; i < 16; i++) acc[i] = 0.f;
    const uint4* base = (const uint4*)xt2h;   // node row = 72 uint4 (1152B)
    union { uint4 u; __half2 h2[4]; } c0;
    for (int e = e0 + w; e < e1; e += 4) {
        const uint4* p0 = base + (size_t)ssrc[e] * 72;
        c0.u = p0[q];
#pragma unroll
        for (int j = 0; j < 4; j++) {
            float2 f = __half22float2(c0.h2[j]);
            acc[2 * j] += f.x;
            acc[2 * j + 1] += f.y;
        }
        if (q < 8) {
            c0.u = p0[64 + q];
#pragma unroll
            for (int j = 0; j < 4; j++) {
                float2 f = __half22float2(c0.h2[j]);
                acc[8 + 2 * j] += f.x;
                acc[9 + 2 * j] += f.y;
            }
        }
    }
#pragma unroll
    for (int j = 0; j < 8; j++) sPart[w][q * 8 + j] = acc[j];
    if (q < 8) {
#pragma unroll
        for (int j = 0; j < 8; j++) sPart[w][512 + q * 8 + j] = acc[8 + j];
    }
    __syncthreads();
    float inv = 1.f / fmaxf((float)(e1 - e0), 1.f);
    for (int i = t; i < 1024; i += 256)
        sT[i] = (i < 576) ? (sPart[0][i] + sPart[1][i] + sPart[2][i] + sPart[3][i]) * inv : 0.f;
    __syncthreads();

    // phase B: MFMA
    int lb = q & 15;
    int hg = q >> 4;
    half8 aF[2];
#pragma unroll
    for (int ks = 0; ks < 2; ks++) {
#pragma unroll
        for (int j = 0; j < 8; j++) {
            int k = ks * 32 + hg * 8 + j;
            aF[ks][j] = (_Float16)sT[k * 16 + lb];
        }
    }
    float y0[4] = {0.f, 0.f, 0.f, 0.f};
    float y1[4] = {0.f, 0.f, 0.f, 0.f};
#pragma unroll
    for (int tt = 0; tt < 4; tt++) {
        int tile = w + 4 * tt;
        if (tile >= 14) break;
        floatx4 cacc = {0.f, 0.f, 0.f, 0.f};
#pragma unroll
        for (int ks = 0; ks < 2; ks++) {
            half8 bF = *(const half8*)(W3B + ((size_t)(tile * 2 + ks) * 64 + q) * 8);
            cacc = __builtin_amdgcn_mfma_f32_16x16x32_f16(aF[ks], bF, cacc, 0, 0, 0);
        }
        int col = tile * 16 + lb;
        float bj  = (col < 216) ? b3[col] : 0.f;
        float w40 = (col < 216) ? W4[col * 2] : 0.f;
        float w41 = (col < 216) ? W4[col * 2 + 1] : 0.f;
#pragma unroll
        for (int r = 0; r < 4; r++) {
            float vv = fmaxf(cacc[r] + bj, 0.f);
            y0[r] = fmaf(vv, w40, y0[r]);
            y1[r] = fmaf(vv, w41, y1[r]);
        }
    }
#pragma unroll
    for (int m = 1; m <= 8; m <<= 1) {
#pragma unroll
        for (int r = 0; r < 4; r++) {
            y0[r] += __shfl_xor(y0[r], m, 64);
            y1[r] += __shfl_xor(y1[r], m, 64);
        }
    }
    if (lb == 0) {
#pragma unroll
        for (int r = 0; r < 4; r++) {
            int row = hg * 4 + r;
            sRed[w][row * 2 + 0] = y0[r];
            sRed[w][row * 2 + 1] = y1[r];
        }
    }
    __syncthreads();
    if (t < 32) y[(size_t)d * 32 + t] = sRed[0][t] + sRed[1][t] + sRed[2][t] + sRed[3][t];
}

// layer 4: mean-agg of projected y over edges2, + b4. out[b][n][k].
__global__ void final_kernel(const float* __restrict__ y, const int* __restrict__ offs,
                             const int* __restrict__ ssrc, const float* __restrict__ b4,
                             float* __restrict__ out) {
    int idx = blockIdx.x * blockDim.x + threadIdx.x;
    if (idx >= N2 * 16) return;
    int d = idx >> 4, b = idx & 15;
    int e0 = offs[d], e1 = offs[d + 1];
    float s0 = 0.f, s1 = 0.f;
    for (int e = e0; e < e1; e++) {
        int s = ssrc[e];
        const float2 v = *(const float2*)(y + (size_t)s * 32 + b * 2);
        s0 += v.x; s1 += v.y;
    }
    float inv = 1.f / fmaxf((float)(e1 - e0), 1.f);
    out[b * (N2 * 2) + d * 2 + 0] = s0 * inv + b4[0];
    out[b * (N2 * 2) + d * 2 + 1] = s1 * inv + b4[1];
}

extern "C" void kernel_launch(void* const* d_in, const int* in_sizes, int n_in,
                              void* d_out, int out_size, void* d_ws, size_t ws_size,
                              hipStream_t stream) {
    const float* x   = (const float*)d_in[0];
    const int* n_id  = (const int*)d_in[1];
    const int* ei0   = (const int*)d_in[2];
    const int* ei1   = (const int*)d_in[3];
    const int* ei2   = (const int*)d_in[4];
    const float* W1  = (const float*)d_in[5];
    const float* b1  = (const float*)d_in[6];
    const float* W2  = (const float*)d_in[7];
    const float* b2  = (const float*)d_in[8];
    const float* W3  = (const float*)d_in[9];
    const float* b3  = (const float*)d_in[10];
    const float* W4  = (const float*)d_in[11];
    const float* b4  = (const float*)d_in[12];
    float* out = (float*)d_out;

    char* ws = (char*)d_ws;
    size_t off = 0;
    auto alloc = [&](size_t bytes) -> void* {
        void* p = ws + off;
        off += (bytes + 255) & ~(size_t)255;
        return p;
    };
    __half* xt0h = (__half*)alloc((size_t)N0 * 128 * 2);
    __half* xt1h = (__half*)alloc((size_t)N0 * 128 * 2);
    __half* xt2h = (__half*)alloc((size_t)N0 * 576 * 2);
    float* yb    = (float*)alloc((size_t)N1 * 32 * 4);
    _Float16* W3B = (_Float16*)alloc((size_t)14 * 2 * 64 * 8 * 2);
    int* counts = (int*)alloc((N0 + N1 + N2) * 4);
    int* offs0 = (int*)alloc((N0 + 1) * 4);
    int* offs1 = (int*)alloc((N1 + 1) * 4);
    int* offs2 = (int*)alloc((N2 + 1) * 4);
    int* cur0 = (int*)alloc(N0 * 4);
    int* cur1 = (int*)alloc(N1 * 4);
    int* cur2 = (int*)alloc(N2 * 4);
    int* ss0 = (int*)alloc(E0C * 4);
    int* ss1 = (int*)alloc(E1C * 4);
    int* ss2 = (int*)alloc(E2C * 4);

    int etot = E0C + E1C + E2C;
    init_kernel<<<ZERO_BLOCKS + PREP_BLOCKS, 256, 0, stream>>>(counts, W3, W3B);
    hist_gather<<<HIST_BLOCKS + GATH_BLOCKS, 256, 0, stream>>>(ei0, ei1, ei2, counts, x, n_id, xt0h);
    scan_all<<<3, 1024, 0, stream>>>(counts, offs0, cur0, offs1, cur1, offs2, cur2);
    scatter_all<<<(etot + 255) / 256, 256, 0, stream>>>(ei0, ei1, ei2, cur0, cur1, cur2, ss0, ss1, ss2);
    sage1_kernel<<<N0 / 16, 256, 0, stream>>>(xt0h, offs0, ss0, W1, b1, xt1h);
    sage2_kernel<<<N0 / 16, 256, 0, stream>>>(xt1h, offs0, ss0, W2, b2, xt2h);
    sage3_kernel<<<N1, 256, 0, stream>>>(xt2h, offs1, ss1, W3B, b3, W4, yb);
    final_kernel<<<(N2 * 16 + 255) / 256, 256, 0, stream>>>(yb, offs2, ss2, b4, out);
}

// Round 11
// 119.938 us; speedup vs baseline: 1.7333x; 1.4376x over previous
//
#include <hip/hip_runtime.h>
#include <hip/hip_fp16.h>

#define NTOT 50000
#define N0 20000
#define N1 5000
#define N2 1000
#define E0C 320000
#define E1C 80000
#define E2C 16000
#define BKT 64   // bucket stride; deg ~ Poisson(16), P(deg>63) < 1e-19

#define ZERO_BLOCKS ((N0 + N1 + N2 + 255) / 256)
#define PREP_BLOCKS 56
#define EDGE_BLOCKS ((E0C + E1C + E2C + 255) / 256)
#define GATH_BLOCKS ((N0 * 16 + 255) / 256)

typedef _Float16 half8 __attribute__((ext_vector_type(8)));
typedef float floatx4 __attribute__((ext_vector_type(4)));

// fused: zero per-dst cursors (ONE contiguous array)  +  W3 pre-swizzle
__global__ void init_kernel(int* __restrict__ cur, const float* __restrict__ W3,
                            _Float16* __restrict__ W3B) {
    int blk = blockIdx.x;
    if (blk < ZERO_BLOCKS) {
        int i = blk * 256 + threadIdx.x;
        if (i < N0 + N1 + N2) cur[i] = 0;
    } else {
        int idx = (blk - ZERO_BLOCKS) * 256 + threadIdx.x;
        if (idx < 14 * 2 * 64 * 8) {
            int j = idx & 7;
            int l = (idx >> 3) & 63;
            int ks = (idx >> 9) & 1;
            int t = idx >> 10;
            int k = ks * 32 + (l >> 4) * 8 + j;
            int col = t * 16 + (l & 15);
            float v = (k < 36 && col < 216) ? W3[k * 216 + col] : 0.f;
            W3B[idx] = (_Float16)v;
        }
    }
}

// fused: bucket-scatter all 3 edge lists (no hist/scan needed)  +  x gather->fp16
// ssX[d*BKT + pos] = src;  degX[d] = final cursor value
__global__ void scatter_gather(const int* __restrict__ ei0, const int* __restrict__ ei1,
                               const int* __restrict__ ei2,
                               int* __restrict__ cur0, int* __restrict__ cur1, int* __restrict__ cur2,
                               int* __restrict__ ss0, int* __restrict__ ss1, int* __restrict__ ss2,
                               const float* __restrict__ x, const int* __restrict__ n_id,
                               __half* __restrict__ xt0h) {
    int blk = blockIdx.x;
    if (blk < EDGE_BLOCKS) {
        int i = blk * 256 + threadIdx.x;
        if (i < E0C) {
            int d = ei0[E0C + i];
            int pos = atomicAdd(&cur0[d], 1);
            ss0[d * BKT + pos] = ei0[i];
        } else if (i < E0C + E1C) {
            int j = i - E0C;
            int d = ei1[E1C + j];
            int pos = atomicAdd(&cur1[d], 1);
            ss1[d * BKT + pos] = ei1[j];
        } else if (i < E0C + E1C + E2C) {
            int j = i - E0C - E1C;
            int d = ei2[E2C + j];
            int pos = atomicAdd(&cur2[d], 1);
            ss2[d * BKT + pos] = ei2[j];
        }
    } else {
        int idx = (blk - EDGE_BLOCKS) * 256 + threadIdx.x;
        if (idx < N0 * 16) {
            int n = idx >> 4, b = idx & 15;
            const float* p = x + (size_t)b * (NTOT * 5) + (size_t)n_id[n] * 5;
            union { __half h[8]; uint4 u; } pk;
#pragma unroll
            for (int c = 0; c < 5; c++) pk.h[c] = __float2half_rn(p[c]);
            pk.h[5] = __half(0.f);
            pk.h[6] = __half(0.f);
            pk.h[7] = __half(0.f);
            *(uint4*)(xt0h + (size_t)n * 128 + b * 8) = pk.u;
        }
    }
}

// SAGE layer 1: quarter-wave per dst; fp16 in (1 uint4/edge), fp16 out; unroll x4
__global__ __launch_bounds__(256) void sage1_kernel(
    const __half* __restrict__ xt0h, const int* __restrict__ deg, const int* __restrict__ ssrc,
    const float* __restrict__ W, const float* __restrict__ bias, __half* __restrict__ xt1h) {
    int gtid = blockIdx.x * blockDim.x + threadIdx.x;
    int wid = gtid >> 6;
    int lane = threadIdx.x & 63;
    int d = wid * 4 + (lane >> 4);
    int b = lane & 15;
    if (d >= N0) return;
    union { uint4 u; __half2 h2[4]; } sp;
    sp.u = *(const uint4*)(xt0h + (size_t)d * 128 + b * 8);
    float2 s01 = __half22float2(sp.h2[0]);
    float2 s23 = __half22float2(sp.h2[1]);
    float2 s4x = __half22float2(sp.h2[2]);
    float xs[5] = {s01.x, s01.y, s23.x, s23.y, s4x.x};
    float a[5] = {xs[0], xs[1], xs[2], xs[3], xs[4]};
    int e0 = d * BKT, e1 = e0 + deg[d];
    int e = e0;
    union { uint4 u; __half2 h2[4]; } pk0, pk1, pk2, pk3;
    for (; e + 3 < e1; e += 4) {
        pk0.u = *(const uint4*)(xt0h + (size_t)ssrc[e] * 128 + b * 8);
        pk1.u = *(const uint4*)(xt0h + (size_t)ssrc[e + 1] * 128 + b * 8);
        pk2.u = *(const uint4*)(xt0h + (size_t)ssrc[e + 2] * 128 + b * 8);
        pk3.u = *(const uint4*)(xt0h + (size_t)ssrc[e + 3] * 128 + b * 8);
#pragma unroll
        for (int j = 0; j < 2; j++) {
            float2 v0 = __half22float2(pk0.h2[j]);
            float2 v1 = __half22float2(pk1.h2[j]);
            float2 v2 = __half22float2(pk2.h2[j]);
            float2 v3 = __half22float2(pk3.h2[j]);
            a[2 * j]     += (v0.x + v1.x) + (v2.x + v3.x);
            a[2 * j + 1] += (v0.y + v1.y) + (v2.y + v3.y);
        }
        float2 w0 = __half22float2(pk0.h2[2]);
        float2 w1 = __half22float2(pk1.h2[2]);
        float2 w2 = __half22float2(pk2.h2[2]);
        float2 w3 = __half22float2(pk3.h2[2]);
        a[4] += (w0.x + w1.x) + (w2.x + w3.x);
    }
    for (; e < e1; e++) {
        pk0.u = *(const uint4*)(xt0h + (size_t)ssrc[e] * 128 + b * 8);
        float2 v01 = __half22float2(pk0.h2[0]);
        float2 v23 = __half22float2(pk0.h2[1]);
        float2 v4x = __half22float2(pk0.h2[2]);
        a[0] += v01.x; a[1] += v01.y; a[2] += v23.x; a[3] += v23.y; a[4] += v4x.x;
    }
    float inv = 1.f / (float)(e1 - e0 + 1);
#pragma unroll
    for (int c = 0; c < 5; c++) a[c] *= inv;
    float o[6];
#pragma unroll
    for (int j = 0; j < 6; j++) {
        float acc = bias[j];
#pragma unroll
        for (int i = 0; i < 5; i++) acc += xs[i] * W[i * 6 + j];
#pragma unroll
        for (int i = 0; i < 5; i++) acc += a[i] * W[(5 + i) * 6 + j];
        o[j] = acc;
    }
    float nrm = 0.f;
#pragma unroll
    for (int j = 0; j < 6; j++) nrm += o[j] * o[j];
    float r = 1.f / fmaxf(sqrtf(nrm), 1e-12f);
    union { __half h[8]; uint4 u; } pk;
#pragma unroll
    for (int j = 0; j < 6; j++) pk.h[j] = __float2half_rn(fmaxf(o[j] * r, 0.f));
    pk.h[6] = __half(0.f);
    pk.h[7] = __half(0.f);
    *(uint4*)(xt1h + (size_t)d * 128 + b * 8) = pk.u;
}

// SAGE layer 2: quarter-wave per dst; fp16 in (1 uint4/edge, unroll x4),
// writes xt2h TRANSPOSED fp16: xt2h[d][c][b] (c<36, b<16)
__global__ __launch_bounds__(256) void sage2_kernel(
    const __half* __restrict__ xt1h, const int* __restrict__ deg, const int* __restrict__ ssrc,
    const float* __restrict__ W, const float* __restrict__ bias, __half* __restrict__ xt2h) {
    int gtid = blockIdx.x * blockDim.x + threadIdx.x;
    int wid = gtid >> 6;
    int lane = threadIdx.x & 63;
    int d = wid * 4 + (lane >> 4);
    int b = lane & 15;
    if (d >= N0) return;
    const __half2* ps = (const __half2*)(xt1h + (size_t)d * 128 + b * 8);
    float2 s01 = __half22float2(ps[0]);
    float2 s23 = __half22float2(ps[1]);
    float2 s45 = __half22float2(ps[2]);
    float xs[6] = {s01.x, s01.y, s23.x, s23.y, s45.x, s45.y};
    float a[6] = {xs[0], xs[1], xs[2], xs[3], xs[4], xs[5]};
    int e0 = d * BKT, e1 = e0 + deg[d];
    int e = e0;
    union { uint4 u; __half2 h2[4]; } pk0, pk1, pk2, pk3;
    for (; e + 3 < e1; e += 4) {
        pk0.u = *(const uint4*)(xt1h + (size_t)ssrc[e] * 128 + b * 8);
        pk1.u = *(const uint4*)(xt1h + (size_t)ssrc[e + 1] * 128 + b * 8);
        pk2.u = *(const uint4*)(xt1h + (size_t)ssrc[e + 2] * 128 + b * 8);
        pk3.u = *(const uint4*)(xt1h + (size_t)ssrc[e + 3] * 128 + b * 8);
#pragma unroll
        for (int j = 0; j < 3; j++) {
            float2 v0 = __half22float2(pk0.h2[j]);
            float2 v1 = __half22float2(pk1.h2[j]);
            float2 v2 = __half22float2(pk2.h2[j]);
            float2 v3 = __half22float2(pk3.h2[j]);
            a[2 * j]     += (v0.x + v1.x) + (v2.x + v3.x);
            a[2 * j + 1] += (v0.y + v1.y) + (v2.y + v3.y);
        }
    }
    for (; e < e1; e++) {
        pk0.u = *(const uint4*)(xt1h + (size_t)ssrc[e] * 128 + b * 8);
#pragma unroll
        for (int j = 0; j < 3; j++) {
            float2 v0 = __half22float2(pk0.h2[j]);
            a[2 * j] += v0.x;
            a[2 * j + 1] += v0.y;
        }
    }
    float inv = 1.f / (float)(e1 - e0 + 1);
#pragma unroll
    for (int c = 0; c < 6; c++) a[c] *= inv;
    float o[36];
#pragma unroll
    for (int j = 0; j < 36; j++) {
        float acc = bias[j];
#pragma unroll
        for (int i = 0; i < 6; i++) acc += xs[i] * W[i * 36 + j];
#pragma unroll
        for (int i = 0; i < 6; i++) acc += a[i] * W[(6 + i) * 36 + j];
        o[j] = acc;
    }
    float nrm = 0.f;
#pragma unroll
    for (int j = 0; j < 36; j++) nrm += o[j] * o[j];
    float r = 1.f / fmaxf(sqrtf(nrm), 1e-12f);
    __half* pd = xt2h + (size_t)d * 576 + b;   // [d][c][b] layout, stride 16 per c
#pragma unroll
    for (int j = 0; j < 36; j++) pd[j * 16] = __float2half_rn(fmaxf(o[j] * r, 0.f));
}

// Fused layer-3: one 256-thread BLOCK per dst (4 waves).
// Phase A: 4 waves split edges (strided), fp32 partials -> LDS reduce into
//          sT[k*16+b] (K zero-padded to 64).
// Phase B: MFMA 16x16x32_f16. A-frag from sT, B-frag = W3B (pre-swizzled).
__global__ __launch_bounds__(256) void sage3_kernel(
    const __half* __restrict__ xt2h, const int* __restrict__ deg, const int* __restrict__ ssrc,
    const _Float16* __restrict__ W3B, const float* __restrict__ b3,
    const float* __restrict__ W4, float* __restrict__ y) {
    __shared__ float sPart[4][576];
    __shared__ float sT[1024];       // [k][b], k<64 (zero-padded), b<16
    __shared__ float sRed[4][32];
    int t = threadIdx.x;
    int w = t >> 6, q = t & 63;
    int d = blockIdx.x;
    int e0 = d * BKT, e1 = e0 + deg[d];

    // phase A: strided 4-way edge split
    float acc[16];
#pragma unroll
    for (int i = 0; i < 16; i++) acc[i] = 0.f;
    const uint4* base = (const uint4*)xt2h;   // node row = 72 uint4 (1152B)
    union { uint4 u; __half2 h2[4]; } c0;
    for (int e = e0 + w; e < e1; e += 4) {
        const uint4* p0 = base + (size_t)ssrc[e] * 72;
        c0.u = p0[q];
#pragma unroll
        for (int j = 0; j < 4; j++) {
            float2 f = __half22float2(c0.h2[j]);
            acc[2 * j] += f.x;
            acc[2 * j + 1] += f.y;
        }
        if (q < 8) {
            c0.u = p0[64 + q];
#pragma unroll
            for (int j = 0; j < 4; j++) {
                float2 f = __half22float2(c0.h2[j]);
                acc[8 + 2 * j] += f.x;
                acc[9 + 2 * j] += f.y;
            }
        }
    }
#pragma unroll
    for (int j = 0; j < 8; j++) sPart[w][q * 8 + j] = acc[j];
    if (q < 8) {
#pragma unroll
        for (int j = 0; j < 8; j++) sPart[w][512 + q * 8 + j] = acc[8 + j];
    }
    __syncthreads();
    float inv = 1.f / fmaxf((float)(e1 - e0), 1.f);
    for (int i = t; i < 1024; i += 256)
        sT[i] = (i < 576) ? (sPart[0][i] + sPart[1][i] + sPart[2][i] + sPart[3][i]) * inv : 0.f;
    __syncthreads();

    // phase B: MFMA
    int lb = q & 15;
    int hg = q >> 4;
    half8 aF[2];
#pragma unroll
    for (int ks = 0; ks < 2; ks++) {
#pragma unroll
        for (int j = 0; j < 8; j++) {
            int k = ks * 32 + hg * 8 + j;
            aF[ks][j] = (_Float16)sT[k * 16 + lb];
        }
    }
    float y0[4] = {0.f, 0.f, 0.f, 0.f};
    float y1[4] = {0.f, 0.f, 0.f, 0.f};
#pragma unroll
    for (int tt = 0; tt < 4; tt++) {
        int tile = w + 4 * tt;
        if (tile >= 14) break;
        floatx4 cacc = {0.f, 0.f, 0.f, 0.f};
#pragma unroll
        for (int ks = 0; ks < 2; ks++) {
            half8 bF = *(const half8*)(W3B + ((size_t)(tile * 2 + ks) * 64 + q) * 8);
            cacc = __builtin_amdgcn_mfma_f32_16x16x32_f16(aF[ks], bF, cacc, 0, 0, 0);
        }
        int col = tile * 16 + lb;
        float bj  = (col < 216) ? b3[col] : 0.f;
        float w40 = (col < 216) ? W4[col * 2] : 0.f;
        float w41 = (col < 216) ? W4[col * 2 + 1] : 0.f;
#pragma unroll
        for (int r = 0; r < 4; r++) {
            float vv = fmaxf(cacc[r] + bj, 0.f);
            y0[r] = fmaf(vv, w40, y0[r]);
            y1[r] = fmaf(vv, w41, y1[r]);
        }
    }
#pragma unroll
    for (int m = 1; m <= 8; m <<= 1) {
#pragma unroll
        for (int r = 0; r < 4; r++) {
            y0[r] += __shfl_xor(y0[r], m, 64);
            y1[r] += __shfl_xor(y1[r], m, 64);
        }
    }
    if (lb == 0) {
#pragma unroll
        for (int r = 0; r < 4; r++) {
            int row = hg * 4 + r;
            sRed[w][row * 2 + 0] = y0[r];
            sRed[w][row * 2 + 1] = y1[r];
        }
    }
    __syncthreads();
    if (t < 32) y[(size_t)d * 32 + t] = sRed[0][t] + sRed[1][t] + sRed[2][t] + sRed[3][t];
}

// layer 4: mean-agg of projected y over edges2, + b4. out[b][n][k].
__global__ void final_kernel(const float* __restrict__ y, const int* __restrict__ deg,
                             const int* __restrict__ ssrc, const float* __restrict__ b4,
                             float* __restrict__ out) {
    int idx = blockIdx.x * blockDim.x + threadIdx.x;
    if (idx >= N2 * 16) return;
    int d = idx >> 4, b = idx & 15;
    int e0 = d * BKT, e1 = e0 + deg[d];
    float s0 = 0.f, s1 = 0.f;
    for (int e = e0; e < e1; e++) {
        int s = ssrc[e];
        const float2 v = *(const float2*)(y + (size_t)s * 32 + b * 2);
        s0 += v.x; s1 += v.y;
    }
    float inv = 1.f / fmaxf((float)(e1 - e0), 1.f);
    out[b * (N2 * 2) + d * 2 + 0] = s0 * inv + b4[0];
    out[b * (N2 * 2) + d * 2 + 1] = s1 * inv + b4[1];
}

extern "C" void kernel_launch(void* const* d_in, const int* in_sizes, int n_in,
                              void* d_out, int out_size, void* d_ws, size_t ws_size,
                              hipStream_t stream) {
    const float* x   = (const float*)d_in[0];
    const int* n_id  = (const int*)d_in[1];
    const int* ei0   = (const int*)d_in[2];
    const int* ei1   = (const int*)d_in[3];
    const int* ei2   = (const int*)d_in[4];
    const float* W1  = (const float*)d_in[5];
    const float* b1  = (const float*)d_in[6];
    const float* W2  = (const float*)d_in[7];
    const float* b2  = (const float*)d_in[8];
    const float* W3  = (const float*)d_in[9];
    const float* b3  = (const float*)d_in[10];
    const float* W4  = (const float*)d_in[11];
    const float* b4  = (const float*)d_in[12];
    float* out = (float*)d_out;

    char* ws = (char*)d_ws;
    size_t off = 0;
    auto alloc = [&](size_t bytes) -> void* {
        void* p = ws + off;
        off += (bytes + 255) & ~(size_t)255;
        return p;
    };
    __half* xt0h = (__half*)alloc((size_t)N0 * 128 * 2);
    __half* xt1h = (__half*)alloc((size_t)N0 * 128 * 2);
    __half* xt2h = (__half*)alloc((size_t)N0 * 576 * 2);
    float* yb    = (float*)alloc((size_t)N1 * 32 * 4);
    _Float16* W3B = (_Float16*)alloc((size_t)14 * 2 * 64 * 8 * 2);
    int* cur  = (int*)alloc((size_t)(N0 + N1 + N2) * 4);   // ONE contiguous cursor array
    int* cur0 = cur;
    int* cur1 = cur + N0;
    int* cur2 = cur + N0 + N1;
    int* ss0 = (int*)alloc((size_t)N0 * BKT * 4);
    int* ss1 = (int*)alloc((size_t)N1 * BKT * 4);
    int* ss2 = (int*)alloc((size_t)N2 * BKT * 4);

    init_kernel<<<ZERO_BLOCKS + PREP_BLOCKS, 256, 0, stream>>>(cur, W3, W3B);
    scatter_gather<<<EDGE_BLOCKS + GATH_BLOCKS, 256, 0, stream>>>(
        ei0, ei1, ei2, cur0, cur1, cur2, ss0, ss1, ss2, x, n_id, xt0h);
    sage1_kernel<<<N0 / 16, 256, 0, stream>>>(xt0h, cur0, ss0, W1, b1, xt1h);
    sage2_kernel<<<N0 / 16, 256, 0, stream>>>(xt1h, cur0, ss0, W2, b2, xt2h);
    sage3_kernel<<<N1, 256, 0, stream>>>(xt2h, cur1, ss1, W3B, b3, W4, yb);
    final_kernel<<<(N2 * 16 + 255) / 256, 256, 0, stream>>>(yb, cur2, ss2, b4, out);
}

// Round 12
// 113.537 us; speedup vs baseline: 1.8311x; 1.0564x over previous
//
#include <hip/hip_runtime.h>
#include <hip/hip_fp16.h>

#define NTOT 50000
#define N0 20000
#define N1 5000
#define N2 1000
#define E0C 320000
#define E1C 80000
#define E2C 16000
#define BKT 64   // bucket stride; deg ~ Poisson(16), P(deg>63) < 1e-19

#define ZERO_BLOCKS ((N0 + N1 + N2 + 255) / 256)
#define PREP_BLOCKS 56
#define EDGE_BLOCKS ((E0C + E1C + E2C + 255) / 256)
#define GATH_BLOCKS ((N0 * 16 + 255) / 256)

typedef _Float16 half8 __attribute__((ext_vector_type(8)));
typedef float floatx4 __attribute__((ext_vector_type(4)));

// fused: zero per-dst cursors (ONE contiguous array)  +  W3 pre-swizzle
__global__ void init_kernel(int* __restrict__ cur, const float* __restrict__ W3,
                            _Float16* __restrict__ W3B) {
    int blk = blockIdx.x;
    if (blk < ZERO_BLOCKS) {
        int i = blk * 256 + threadIdx.x;
        if (i < N0 + N1 + N2) cur[i] = 0;
    } else {
        int idx = (blk - ZERO_BLOCKS) * 256 + threadIdx.x;
        if (idx < 14 * 2 * 64 * 8) {
            int j = idx & 7;
            int l = (idx >> 3) & 63;
            int ks = (idx >> 9) & 1;
            int t = idx >> 10;
            int k = ks * 32 + (l >> 4) * 8 + j;
            int col = t * 16 + (l & 15);
            float v = (k < 36 && col < 216) ? W3[k * 216 + col] : 0.f;
            W3B[idx] = (_Float16)v;
        }
    }
}

// fused: bucket-scatter all 3 edge lists  +  x gather->fp16
__global__ void scatter_gather(const int* __restrict__ ei0, const int* __restrict__ ei1,
                               const int* __restrict__ ei2,
                               int* __restrict__ cur0, int* __restrict__ cur1, int* __restrict__ cur2,
                               int* __restrict__ ss0, int* __restrict__ ss1, int* __restrict__ ss2,
                               const float* __restrict__ x, const int* __restrict__ n_id,
                               __half* __restrict__ xt0h) {
    int blk = blockIdx.x;
    if (blk < EDGE_BLOCKS) {
        int i = blk * 256 + threadIdx.x;
        if (i < E0C) {
            int d = ei0[E0C + i];
            int pos = atomicAdd(&cur0[d], 1);
            ss0[d * BKT + pos] = ei0[i];
        } else if (i < E0C + E1C) {
            int j = i - E0C;
            int d = ei1[E1C + j];
            int pos = atomicAdd(&cur1[d], 1);
            ss1[d * BKT + pos] = ei1[j];
        } else if (i < E0C + E1C + E2C) {
            int j = i - E0C - E1C;
            int d = ei2[E2C + j];
            int pos = atomicAdd(&cur2[d], 1);
            ss2[d * BKT + pos] = ei2[j];
        }
    } else {
        int idx = (blk - EDGE_BLOCKS) * 256 + threadIdx.x;
        if (idx < N0 * 16) {
            int n = idx >> 4, b = idx & 15;
            const float* p = x + (size_t)b * (NTOT * 5) + (size_t)n_id[n] * 5;
            union { __half h[8]; uint4 u; } pk;
#pragma unroll
            for (int c = 0; c < 5; c++) pk.h[c] = __float2half_rn(p[c]);
            pk.h[5] = __half(0.f);
            pk.h[6] = __half(0.f);
            pk.h[7] = __half(0.f);
            *(uint4*)(xt0h + (size_t)n * 128 + b * 8) = pk.u;
        }
    }
}

// SAGE layer 1: quarter-wave per dst; fp16 in (1 uint4/edge), fp16 out; unroll x8
__global__ __launch_bounds__(256) void sage1_kernel(
    const __half* __restrict__ xt0h, const int* __restrict__ deg, const int* __restrict__ ssrc,
    const float* __restrict__ W, const float* __restrict__ bias, __half* __restrict__ xt1h) {
    int gtid = blockIdx.x * blockDim.x + threadIdx.x;
    int wid = gtid >> 6;
    int lane = threadIdx.x & 63;
    int d = wid * 4 + (lane >> 4);
    int b = lane & 15;
    if (d >= N0) return;
    union { uint4 u; __half2 h2[4]; } sp;
    sp.u = *(const uint4*)(xt0h + (size_t)d * 128 + b * 8);
    float2 s01 = __half22float2(sp.h2[0]);
    float2 s23 = __half22float2(sp.h2[1]);
    float2 s4x = __half22float2(sp.h2[2]);
    float xs[5] = {s01.x, s01.y, s23.x, s23.y, s4x.x};
    float a[5] = {xs[0], xs[1], xs[2], xs[3], xs[4]};
    int e0 = d * BKT, e1 = e0 + deg[d];
    int e = e0;
    union { uint4 u; __half2 h2[4]; } pk[8];
    for (; e + 7 < e1; e += 8) {
#pragma unroll
        for (int u = 0; u < 8; u++)
            pk[u].u = *(const uint4*)(xt0h + (size_t)ssrc[e + u] * 128 + b * 8);
#pragma unroll
        for (int u = 0; u < 8; u++) {
            float2 v01 = __half22float2(pk[u].h2[0]);
            float2 v23 = __half22float2(pk[u].h2[1]);
            float2 v4x = __half22float2(pk[u].h2[2]);
            a[0] += v01.x; a[1] += v01.y; a[2] += v23.x; a[3] += v23.y; a[4] += v4x.x;
        }
    }
    for (; e + 3 < e1; e += 4) {
#pragma unroll
        for (int u = 0; u < 4; u++)
            pk[u].u = *(const uint4*)(xt0h + (size_t)ssrc[e + u] * 128 + b * 8);
#pragma unroll
        for (int u = 0; u < 4; u++) {
            float2 v01 = __half22float2(pk[u].h2[0]);
            float2 v23 = __half22float2(pk[u].h2[1]);
            float2 v4x = __half22float2(pk[u].h2[2]);
            a[0] += v01.x; a[1] += v01.y; a[2] += v23.x; a[3] += v23.y; a[4] += v4x.x;
        }
    }
    for (; e < e1; e++) {
        pk[0].u = *(const uint4*)(xt0h + (size_t)ssrc[e] * 128 + b * 8);
        float2 v01 = __half22float2(pk[0].h2[0]);
        float2 v23 = __half22float2(pk[0].h2[1]);
        float2 v4x = __half22float2(pk[0].h2[2]);
        a[0] += v01.x; a[1] += v01.y; a[2] += v23.x; a[3] += v23.y; a[4] += v4x.x;
    }
    float inv = 1.f / (float)(e1 - e0 + 1);
#pragma unroll
    for (int c = 0; c < 5; c++) a[c] *= inv;
    float o[6];
#pragma unroll
    for (int j = 0; j < 6; j++) {
        float acc = bias[j];
#pragma unroll
        for (int i = 0; i < 5; i++) acc += xs[i] * W[i * 6 + j];
#pragma unroll
        for (int i = 0; i < 5; i++) acc += a[i] * W[(5 + i) * 6 + j];
        o[j] = acc;
    }
    float nrm = 0.f;
#pragma unroll
    for (int j = 0; j < 6; j++) nrm += o[j] * o[j];
    float r = 1.f / fmaxf(sqrtf(nrm), 1e-12f);
    union { __half h[8]; uint4 u; } pko;
#pragma unroll
    for (int j = 0; j < 6; j++) pko.h[j] = __float2half_rn(fmaxf(o[j] * r, 0.f));
    pko.h[6] = __half(0.f);
    pko.h[7] = __half(0.f);
    *(uint4*)(xt1h + (size_t)d * 128 + b * 8) = pko.u;
}

// SAGE layer 2: quarter-wave per dst; fp16 in (1 uint4/edge, unroll x8),
// writes xt2h TRANSPOSED fp16: xt2h[d][c][b] (c<36, b<16)
__global__ __launch_bounds__(256) void sage2_kernel(
    const __half* __restrict__ xt1h, const int* __restrict__ deg, const int* __restrict__ ssrc,
    const float* __restrict__ W, const float* __restrict__ bias, __half* __restrict__ xt2h) {
    int gtid = blockIdx.x * blockDim.x + threadIdx.x;
    int wid = gtid >> 6;
    int lane = threadIdx.x & 63;
    int d = wid * 4 + (lane >> 4);
    int b = lane & 15;
    if (d >= N0) return;
    const __half2* ps = (const __half2*)(xt1h + (size_t)d * 128 + b * 8);
    float2 s01 = __half22float2(ps[0]);
    float2 s23 = __half22float2(ps[1]);
    float2 s45 = __half22float2(ps[2]);
    float xs[6] = {s01.x, s01.y, s23.x, s23.y, s45.x, s45.y};
    float a[6] = {xs[0], xs[1], xs[2], xs[3], xs[4], xs[5]};
    int e0 = d * BKT, e1 = e0 + deg[d];
    int e = e0;
    union { uint4 u; __half2 h2[4]; } pk[8];
    for (; e + 7 < e1; e += 8) {
#pragma unroll
        for (int u = 0; u < 8; u++)
            pk[u].u = *(const uint4*)(xt1h + (size_t)ssrc[e + u] * 128 + b * 8);
#pragma unroll
        for (int u = 0; u < 8; u++) {
#pragma unroll
            for (int j = 0; j < 3; j++) {
                float2 v = __half22float2(pk[u].h2[j]);
                a[2 * j] += v.x;
                a[2 * j + 1] += v.y;
            }
        }
    }
    for (; e + 3 < e1; e += 4) {
#pragma unroll
        for (int u = 0; u < 4; u++)
            pk[u].u = *(const uint4*)(xt1h + (size_t)ssrc[e + u] * 128 + b * 8);
#pragma unroll
        for (int u = 0; u < 4; u++) {
#pragma unroll
            for (int j = 0; j < 3; j++) {
                float2 v = __half22float2(pk[u].h2[j]);
                a[2 * j] += v.x;
                a[2 * j + 1] += v.y;
            }
        }
    }
    for (; e < e1; e++) {
        pk[0].u = *(const uint4*)(xt1h + (size_t)ssrc[e] * 128 + b * 8);
#pragma unroll
        for (int j = 0; j < 3; j++) {
            float2 v = __half22float2(pk[0].h2[j]);
            a[2 * j] += v.x;
            a[2 * j + 1] += v.y;
        }
    }
    float inv = 1.f / (float)(e1 - e0 + 1);
#pragma unroll
    for (int c = 0; c < 6; c++) a[c] *= inv;
    float o[36];
#pragma unroll
    for (int j = 0; j < 36; j++) {
        float acc = bias[j];
#pragma unroll
        for (int i = 0; i < 6; i++) acc += xs[i] * W[i * 36 + j];
#pragma unroll
        for (int i = 0; i < 6; i++) acc += a[i] * W[(6 + i) * 36 + j];
        o[j] = acc;
    }
    float nrm = 0.f;
#pragma unroll
    for (int j = 0; j < 36; j++) nrm += o[j] * o[j];
    float r = 1.f / fmaxf(sqrtf(nrm), 1e-12f);
    __half* pd = xt2h + (size_t)d * 576 + b;   // [d][c][b] layout, stride 16 per c
#pragma unroll
    for (int j = 0; j < 36; j++) pd[j * 16] = __float2half_rn(fmaxf(o[j] * r, 0.f));
}

// Fused layer-3: one 256-thread BLOCK per dst (4 waves).
// Phase A: 4 waves split edges (strided, unroll x2 -> 2 edges in flight),
//          fp32 partials -> LDS reduce into sT[k*16+b] (K zero-padded to 64).
// Phase B: MFMA 16x16x32_f16. A-frag from sT, B-frag = W3B (pre-swizzled).
__global__ __launch_bounds__(256) void sage3_kernel(
    const __half* __restrict__ xt2h, const int* __restrict__ deg, const int* __restrict__ ssrc,
    const _Float16* __restrict__ W3B, const float* __restrict__ b3,
    const float* __restrict__ W4, float* __restrict__ y) {
    __shared__ float sPart[4][576];
    __shared__ float sT[1024];       // [k][b], k<64 (zero-padded), b<16
    __shared__ float sRed[4][32];
    int t = threadIdx.x;
    int w = t >> 6, q = t & 63;
    int d = blockIdx.x;
    int e0 = d * BKT, e1 = e0 + deg[d];

    // phase A: strided 4-way edge split, 2 edges in flight
    float acc[16];
#pragma unroll
    for (int i = 0; i < 16; i++) acc[i] = 0.f;
    const uint4* base = (const uint4*)xt2h;   // node row = 72 uint4 (1152B)
    union { uint4 u; __half2 h2[4]; } c0, c1, d0, d1;
    int e = e0 + w;
    for (; e + 4 < e1; e += 8) {
        int s0 = ssrc[e], s1 = ssrc[e + 4];
        const uint4* p0 = base + (size_t)s0 * 72;
        const uint4* p1 = base + (size_t)s1 * 72;
        c0.u = p0[q];
        c1.u = p1[q];
        if (q < 8) { d0.u = p0[64 + q]; d1.u = p1[64 + q]; }
#pragma unroll
        for (int j = 0; j < 4; j++) {
            float2 f0 = __half22float2(c0.h2[j]);
            float2 f1 = __half22float2(c1.h2[j]);
            acc[2 * j] += f0.x + f1.x;
            acc[2 * j + 1] += f0.y + f1.y;
        }
        if (q < 8) {
#pragma unroll
            for (int j = 0; j < 4; j++) {
                float2 f0 = __half22float2(d0.h2[j]);
                float2 f1 = __half22float2(d1.h2[j]);
                acc[8 + 2 * j] += f0.x + f1.x;
                acc[9 + 2 * j] += f0.y + f1.y;
            }
        }
    }
    for (; e < e1; e += 4) {
        const uint4* p0 = base + (size_t)ssrc[e] * 72;
        c0.u = p0[q];
        if (q < 8) d0.u = p0[64 + q];
#pragma unroll
        for (int j = 0; j < 4; j++) {
            float2 f = __half22float2(c0.h2[j]);
            acc[2 * j] += f.x;
            acc[2 * j + 1] += f.y;
        }
        if (q < 8) {
#pragma unroll
            for (int j = 0; j < 4; j++) {
                float2 f = __half22float2(d0.h2[j]);
                acc[8 + 2 * j] += f.x;
                acc[9 + 2 * j] += f.y;
            }
        }
    }
#pragma unroll
    for (int j = 0; j < 8; j++) sPart[w][q * 8 + j] = acc[j];
    if (q < 8) {
#pragma unroll
        for (int j = 0; j < 8; j++) sPart[w][512 + q * 8 + j] = acc[8 + j];
    }
    __syncthreads();
    float inv = 1.f / fmaxf((float)(e1 - e0), 1.f);
    for (int i = t; i < 1024; i += 256)
        sT[i] = (i < 576) ? (sPart[0][i] + sPart[1][i] + sPart[2][i] + sPart[3][i]) * inv : 0.f;
    __syncthreads();

    // phase B: MFMA
    int lb = q & 15;
    int hg = q >> 4;
    half8 aF[2];
#pragma unroll
    for (int ks = 0; ks < 2; ks++) {
#pragma unroll
        for (int j = 0; j < 8; j++) {
            int k = ks * 32 + hg * 8 + j;
            aF[ks][j] = (_Float16)sT[k * 16 + lb];
        }
    }
    float y0[4] = {0.f, 0.f, 0.f, 0.f};
    float y1[4] = {0.f, 0.f, 0.f, 0.f};
#pragma unroll
    for (int tt = 0; tt < 4; tt++) {
        int tile = w + 4 * tt;
        if (tile >= 14) break;
        floatx4 cacc = {0.f, 0.f, 0.f, 0.f};
#pragma unroll
        for (int ks = 0; ks < 2; ks++) {
            half8 bF = *(const half8*)(W3B + ((size_t)(tile * 2 + ks) * 64 + q) * 8);
            cacc = __builtin_amdgcn_mfma_f32_16x16x32_f16(aF[ks], bF, cacc, 0, 0, 0);
        }
        int col = tile * 16 + lb;
        float bj  = (col < 216) ? b3[col] : 0.f;
        float w40 = (col < 216) ? W4[col * 2] : 0.f;
        float w41 = (col < 216) ? W4[col * 2 + 1] : 0.f;
#pragma unroll
        for (int r = 0; r < 4; r++) {
            float vv = fmaxf(cacc[r] + bj, 0.f);
            y0[r] = fmaf(vv, w40, y0[r]);
            y1[r] = fmaf(vv, w41, y1[r]);
        }
    }
#pragma unroll
    for (int m = 1; m <= 8; m <<= 1) {
#pragma unroll
        for (int r = 0; r < 4; r++) {
            y0[r] += __shfl_xor(y0[r], m, 64);
            y1[r] += __shfl_xor(y1[r], m, 64);
        }
    }
    if (lb == 0) {
#pragma unroll
        for (int r = 0; r < 4; r++) {
            int row = hg * 4 + r;
            sRed[w][row * 2 + 0] = y0[r];
            sRed[w][row * 2 + 1] = y1[r];
        }
    }
    __syncthreads();
    if (t < 32) y[(size_t)d * 32 + t] = sRed[0][t] + sRed[1][t] + sRed[2][t] + sRed[3][t];
}

// layer 4: mean-agg of projected y over edges2, + b4. out[b][n][k].
__global__ void final_kernel(const float* __restrict__ y, const int* __restrict__ deg,
                             const int* __restrict__ ssrc, const float* __restrict__ b4,
                             float* __restrict__ out) {
    int idx = blockIdx.x * blockDim.x + threadIdx.x;
    if (idx >= N2 * 16) return;
    int d = idx >> 4, b = idx & 15;
    int e0 = d * BKT, e1 = e0 + deg[d];
    float s0 = 0.f, s1 = 0.f;
    for (int e = e0; e < e1; e++) {
        int s = ssrc[e];
        const float2 v = *(const float2*)(y + (size_t)s * 32 + b * 2);
        s0 += v.x; s1 += v.y;
    }
    float inv = 1.f / fmaxf((float)(e1 - e0), 1.f);
    out[b * (N2 * 2) + d * 2 + 0] = s0 * inv + b4[0];
    out[b * (N2 * 2) + d * 2 + 1] = s1 * inv + b4[1];
}

extern "C" void kernel_launch(void* const* d_in, const int* in_sizes, int n_in,
                              void* d_out, int out_size, void* d_ws, size_t ws_size,
                              hipStream_t stream) {
    const float* x   = (const float*)d_in[0];
    const int* n_id  = (const int*)d_in[1];
    const int* ei0   = (const int*)d_in[2];
    const int* ei1   = (const int*)d_in[3];
    const int* ei2   = (const int*)d_in[4];
    const float* W1  = (const float*)d_in[5];
    const float* b1  = (const float*)d_in[6];
    const float* W2  = (const float*)d_in[7];
    const float* b2  = (const float*)d_in[8];
    const float* W3  = (const float*)d_in[9];
    const float* b3  = (const float*)d_in[10];
    const float* W4  = (const float*)d_in[11];
    const float* b4  = (const float*)d_in[12];
    float* out = (float*)d_out;

    char* ws = (char*)d_ws;
    size_t off = 0;
    auto alloc = [&](size_t bytes) -> void* {
        void* p = ws + off;
        off += (bytes + 255) & ~(size_t)255;
        return p;
    };
    __half* xt0h = (__half*)alloc((size_t)N0 * 128 * 2);
    __half* xt1h = (__half*)alloc((size_t)N0 * 128 * 2);
    __half* xt2h = (__half*)alloc((size_t)N0 * 576 * 2);
    float* yb    = (float*)alloc((size_t)N1 * 32 * 4);
    _Float16* W3B = (_Float16*)alloc((size_t)14 * 2 * 64 * 8 * 2);
    int* cur  = (int*)alloc((size_t)(N0 + N1 + N2) * 4);   // ONE contiguous cursor array
    int* cur0 = cur;
    int* cur1 = cur + N0;
    int* cur2 = cur + N0 + N1;
    int* ss0 = (int*)alloc((size_t)N0 * BKT * 4);
    int* ss1 = (int*)alloc((size_t)N1 * BKT * 4);
    int* ss2 = (int*)alloc((size_t)N2 * BKT * 4);

    init_kernel<<<ZERO_BLOCKS + PREP_BLOCKS, 256, 0, stream>>>(cur, W3, W3B);
    scatter_gather<<<EDGE_BLOCKS + GATH_BLOCKS, 256, 0, stream>>>(
        ei0, ei1, ei2, cur0, cur1, cur2, ss0, ss1, ss2, x, n_id, xt0h);
    sage1_kernel<<<N0 / 16, 256, 0, stream>>>(xt0h, cur0, ss0, W1, b1, xt1h);
    sage2_kernel<<<N0 / 16, 256, 0, stream>>>(xt1h, cur0, ss0, W2, b2, xt2h);
    sage3_kernel<<<N1, 256, 0, stream>>>(xt2h, cur1, ss1, W3B, b3, W4, yb);
    final_kernel<<<(N2 * 16 + 255) / 256, 256, 0, stream>>>(yb, cur2, ss2, b4, out);
}